// Round 2
// baseline (251.574 us; speedup 1.0000x reference)
//
#include <hip/hip_runtime.h>
#include <hip/hip_bf16.h>

// ---------------------------------------------------------------------------
// OrthoInitPhasor round 8
//   prep_all:     cvt x->bf16, pack Wv/Wo, cvt Wkm/Wqm, transpose Wk/Wq,
//                 compose biases
//   gemm_compose: Wkk = Wkm@Wk, Wqq = Wqm@Wq via MFMA
//   gemm_bt:      x @ [Wv|Wkk|Wqq]^T + bias -> VKQ planar [16384,1536] bf16
//                 (XCD-swizzled grid, 2 K-slices staged per barrier pair)
//   phasor_scan:  512 blocks (chunk x dim-half), 2-seg split-scan phasor +
//                 cumsum, partial rows in LDS, writes retrieved bf16 -> Rg
//                 (reuses x_bf buffer; x_bf is dead after gemm_bt)
//   ln_gemm:      512 blocks (32 rows), LN + MFMA GEMM(Wo) + bo + resid
// ---------------------------------------------------------------------------

typedef __attribute__((ext_vector_type(8))) short short8;   // 8 x bf16
typedef __attribute__((ext_vector_type(4))) float f32x4;

#define M_TOK   16384
#define DIM     512
#define NCHUNK  64
#define NSPAD   520   // LDS row stride (bf16 elems) for normed tile in ln_gemm

__device__ __forceinline__ void gll16(const void* g, void* l) {
  __builtin_amdgcn_global_load_lds(
      (const __attribute__((address_space(1))) unsigned int*)g,
      (__attribute__((address_space(3))) unsigned int*)l, 16, 0, 0);
}

__device__ __forceinline__ uint2 pack4bf(float4 v) {
  union { __hip_bfloat16 h[4]; uint2 u; } t;
  t.h[0] = __float2bfloat16(v.x);
  t.h[1] = __float2bfloat16(v.y);
  t.h[2] = __float2bfloat16(v.z);
  t.h[3] = __float2bfloat16(v.w);
  return t.u;
}

__device__ __forceinline__ unsigned int pack2bf(float a, float b) {
  union { __hip_bfloat16 h[2]; unsigned int u; } t;
  t.h[0] = __float2bfloat16(a);
  t.h[1] = __float2bfloat16(b);
  return t.u;
}

__device__ __forceinline__ float u2f(unsigned short u) {
  union { unsigned int i; float f; } t;
  t.i = (unsigned int)u << 16;
  return t.f;
}

// ------------------------------ prep (merged) ------------------------------
__global__ __launch_bounds__(256) void prep_all(
    const float* __restrict__ x, __hip_bfloat16* __restrict__ x_bf,
    const float* __restrict__ Wv, const float* __restrict__ Wo,
    const float* __restrict__ bv,
    const float* __restrict__ Wkm, const float* __restrict__ Wqm,
    const float* __restrict__ Wk, const float* __restrict__ Wq,
    const float* __restrict__ bk, const float* __restrict__ bkm,
    const float* __restrict__ bq, const float* __restrict__ bqm,
    __hip_bfloat16* __restrict__ Wall, float* __restrict__ bc1,
    __hip_bfloat16* __restrict__ Wm_bf, __hip_bfloat16* __restrict__ WT_bf) {
  const int tid = threadIdx.x;
  if (blockIdx.x < 8192) {
    int i = blockIdx.x * 256 + tid;          // 2097152 float4s
    ((uint2*)x_bf)[i] = pack4bf(((const float4*)x)[i]);
    return;
  }
  const int b = blockIdx.x - 8192;
  if (b < 512) {
    int m = b >> 8;
    int idx = ((b & 255) * 256 + tid) * 4;
    const float* src = m ? Wo : Wv;
    __hip_bfloat16* dst = Wall + (m ? (size_t)1536 * 512 : 0);
    ((uint2*)dst)[idx >> 2] = pack4bf(*(const float4*)(src + idx));
    int t = b * 256 + tid;
    if (t < 512) bc1[t] = bv[t];
  } else if (b < 1024) {
    int bb = b - 512;
    int m = bb >> 8;
    int idx = ((bb & 255) * 256 + tid) * 4;
    const float* src = m ? Wqm : Wkm;
    ((uint2*)(Wm_bf + (size_t)m * 262144))[idx >> 2] =
        pack4bf(*(const float4*)(src + idx));
  } else if (b < 1152) {
    __shared__ float tile[64][65];
    int bb = b - 1024;
    int z = bb >> 6;
    int tl = bb & 63;
    int tr = tl >> 3, tc = tl & 7;
    const float* src = z ? Wq : Wk;
#pragma unroll
    for (int i = 0; i < 4; i++) {
      int r = (tid >> 4) + 16 * i;
      int c4 = (tid & 15) * 4;
      float4 v = *(const float4*)(src + (size_t)(tr * 64 + r) * 512 +
                                  tc * 64 + c4);
      tile[r][c4 + 0] = v.x;
      tile[r][c4 + 1] = v.y;
      tile[r][c4 + 2] = v.z;
      tile[r][c4 + 3] = v.w;
    }
    __syncthreads();
    int orow = tid >> 2;
    int seg = tid & 3;
    __hip_bfloat16* dst = WT_bf + (size_t)z * 262144 +
                          (size_t)(tc * 64 + orow) * 512 + tr * 64 + seg * 16;
#pragma unroll
    for (int q = 0; q < 4; q++) {
      float4 v;
      v.x = tile[seg * 16 + q * 4 + 0][orow];
      v.y = tile[seg * 16 + q * 4 + 1][orow];
      v.z = tile[seg * 16 + q * 4 + 2][orow];
      v.w = tile[seg * 16 + q * 4 + 3][orow];
      *(uint2*)(dst + q * 4) = pack4bf(v);
    }
  } else {
    int row = (b - 1152) * 4 + (tid >> 6);
    int lane = tid & 63;
    int z = row >> 9;
    int i = row & 511;
    const float* Wm = z ? Wqm : Wkm;
    const float* b0 = z ? bq : bk;
    const float* bm = z ? bqm : bkm;
    const float4* w4 = (const float4*)(Wm + (size_t)i * 512 + lane * 8);
    const float4* v4 = (const float4*)(b0 + lane * 8);
    float4 w0 = w4[0], w1 = w4[1], c0 = v4[0], c1 = v4[1];
    float acc = w0.x * c0.x + w0.y * c0.y + w0.z * c0.z + w0.w * c0.w +
                w1.x * c1.x + w1.y * c1.y + w1.z * c1.z + w1.w * c1.w;
#pragma unroll
    for (int off = 32; off; off >>= 1) acc += __shfl_xor(acc, off, 64);
    if (lane == 0) bc1[512 + z * 512 + i] = acc + bm[i];
  }
}

// ------------------------------- GEMM (B^T) --------------------------------
// C[m,n] = sum_k A[m,k] * Bt[n,k] + bias[n], bf16 planar store (ldc)
// 1D grid 1536, XCD-swizzled so each XCD owns contiguous M-panels.
// Two BK=32 slices staged per barrier pair.
__global__ __launch_bounds__(256) void gemm_bt(
    const __hip_bfloat16* __restrict__ A, int lda,
    const __hip_bfloat16* __restrict__ Bt,
    const float* __restrict__ bias,
    __hip_bfloat16* __restrict__ Cout, int ldc) {
  constexpr int K = 512, BK = 32;
  __shared__ __align__(16) __hip_bfloat16 As[2][128 * BK];   // 16 KB
  __shared__ __align__(16) __hip_bfloat16 Bs[2][128 * BK];   // 16 KB

  const int tid  = threadIdx.x;
  const int lane = tid & 63;
  const int w    = tid >> 6;
  const int wm   = w >> 1;
  const int wn   = w & 1;
  // bijective XCD swizzle: nwg=1536=8*192
  const int lb = (blockIdx.x & 7) * 192 + (blockIdx.x >> 3);
  const int by = lb / 12;
  const int bx = lb - by * 12;
  const int m0 = by * 128;
  const int n0 = bx * 128;

  const int rS0    = (w * 2 + 0) * 16 + (lane >> 2);
  const int rS1    = (w * 2 + 1) * 16 + (lane >> 2);
  const int kInRow = (lane & 3) * 8;
  const __hip_bfloat16* gA0 = A + (size_t)(m0 + rS0) * lda + kInRow;
  const __hip_bfloat16* gA1 = A + (size_t)(m0 + rS1) * lda + kInRow;
  const __hip_bfloat16* gB0 = Bt + (size_t)(n0 + rS0) * K + kInRow;
  const __hip_bfloat16* gB1 = Bt + (size_t)(n0 + rS1) * K + kInRow;
  char* ldsA0 = (char*)&As[0][0] + (w * 2 + 0) * 1024;
  char* ldsA1 = (char*)&As[0][0] + (w * 2 + 1) * 1024;
  char* ldsB0 = (char*)&Bs[0][0] + (w * 2 + 0) * 1024;
  char* ldsB1 = (char*)&Bs[0][0] + (w * 2 + 1) * 1024;

  f32x4 acc[4][4] = {};

  const int rfA = lane & 15;
  const int rfK = (lane >> 4) * 8;

  for (int kt = 0; kt < K; kt += 2 * BK) {
    __syncthreads();
    gll16(gA0 + kt, ldsA0);
    gll16(gA1 + kt, ldsA1);
    gll16(gB0 + kt, ldsB0);
    gll16(gB1 + kt, ldsB1);
    gll16(gA0 + kt + BK, ldsA0 + 8192);
    gll16(gA1 + kt + BK, ldsA1 + 8192);
    gll16(gB0 + kt + BK, ldsB0 + 8192);
    gll16(gB1 + kt + BK, ldsB1 + 8192);
    __syncthreads();

#pragma unroll
    for (int h = 0; h < 2; h++) {
      const __hip_bfloat16* Ah = &As[h][0];
      const __hip_bfloat16* Bh = &Bs[h][0];
      short8 af[4], bfv[4];
#pragma unroll
      for (int i = 0; i < 4; i++)
        af[i] = *(const short8*)(Ah + (wm * 64 + i * 16 + rfA) * BK + rfK);
#pragma unroll
      for (int j = 0; j < 4; j++)
        bfv[j] = *(const short8*)(Bh + (wn * 64 + j * 16 + rfA) * BK + rfK);
#pragma unroll
      for (int i = 0; i < 4; i++)
#pragma unroll
        for (int j = 0; j < 4; j++)
          acc[i][j] = __builtin_amdgcn_mfma_f32_16x16x32_bf16(
              af[i], bfv[j], acc[i][j], 0, 0, 0);
    }
  }

  const int cq = lane >> 4;
#pragma unroll
  for (int i = 0; i < 4; i++) {
    int row = m0 + wm * 64 + i * 16 + cq * 4;
#pragma unroll
    for (int j = 0; j < 4; j++) {
      int col = n0 + wn * 64 + j * 16 + (lane & 15);
      float bz = bias[col];
#pragma unroll
      for (int r = 0; r < 4; r++) {
        float v = acc[i][j][r] + bz;
        Cout[(size_t)(row + r) * ldc + col] = __float2bfloat16(v);
      }
    }
  }
}

// --------------- compose GEMM: Wkk=Wkm@Wk, Wqq=Wqm@Wq (MFMA) ---------------
__global__ __launch_bounds__(256) void gemm_compose(
    const __hip_bfloat16* __restrict__ Wm_bf,
    const __hip_bfloat16* __restrict__ WT_bf,
    __hip_bfloat16* __restrict__ Wall) {
  constexpr int K = 512, BK = 32;
  const __hip_bfloat16* A  = Wm_bf + (size_t)blockIdx.z * 262144;
  const __hip_bfloat16* Bt = WT_bf + (size_t)blockIdx.z * 262144;
  __hip_bfloat16* C = Wall + (size_t)(512 + blockIdx.z * 512) * 512;
  __shared__ __align__(16) __hip_bfloat16 As[128 * BK];
  __shared__ __align__(16) __hip_bfloat16 Bs[128 * BK];

  const int tid  = threadIdx.x;
  const int lane = tid & 63;
  const int w    = tid >> 6;
  const int wm   = w >> 1;
  const int wn   = w & 1;
  const int m0   = blockIdx.y * 128;
  const int n0   = blockIdx.x * 128;

  const int rS0    = (w * 2 + 0) * 16 + (lane >> 2);
  const int rS1    = (w * 2 + 1) * 16 + (lane >> 2);
  const int kInRow = (lane & 3) * 8;
  const __hip_bfloat16* gA0 = A + (size_t)(m0 + rS0) * K + kInRow;
  const __hip_bfloat16* gA1 = A + (size_t)(m0 + rS1) * K + kInRow;
  const __hip_bfloat16* gB0 = Bt + (size_t)(n0 + rS0) * K + kInRow;
  const __hip_bfloat16* gB1 = Bt + (size_t)(n0 + rS1) * K + kInRow;
  char* ldsA0 = (char*)As + (w * 2 + 0) * 1024;
  char* ldsA1 = (char*)As + (w * 2 + 1) * 1024;
  char* ldsB0 = (char*)Bs + (w * 2 + 0) * 1024;
  char* ldsB1 = (char*)Bs + (w * 2 + 1) * 1024;

  f32x4 acc[4][4] = {};
  const int rfA = lane & 15;
  const int rfK = (lane >> 4) * 8;

  for (int kt = 0; kt < K; kt += BK) {
    __syncthreads();
    gll16(gA0 + kt, ldsA0);
    gll16(gA1 + kt, ldsA1);
    gll16(gB0 + kt, ldsB0);
    gll16(gB1 + kt, ldsB1);
    __syncthreads();

    short8 af[4], bf[4];
#pragma unroll
    for (int i = 0; i < 4; i++)
      af[i] = *(const short8*)(As + (wm * 64 + i * 16 + rfA) * BK + rfK);
#pragma unroll
    for (int j = 0; j < 4; j++)
      bf[j] = *(const short8*)(Bs + (wn * 64 + j * 16 + rfA) * BK + rfK);
#pragma unroll
    for (int i = 0; i < 4; i++)
#pragma unroll
      for (int j = 0; j < 4; j++)
        acc[i][j] = __builtin_amdgcn_mfma_f32_16x16x32_bf16(
            af[i], bf[j], acc[i][j], 0, 0, 0);
  }

  const int cq = lane >> 4;
#pragma unroll
  for (int i = 0; i < 4; i++) {
    int row = m0 + wm * 64 + i * 16 + cq * 4;
#pragma unroll
    for (int j = 0; j < 4; j++) {
      int col = n0 + wn * 64 + j * 16 + (lane & 15);
#pragma unroll
      for (int r = 0; r < 4; r++)
        C[(size_t)(row + r) * 512 + col] = __float2bfloat16(acc[i][j][r]);
    }
  }
}

// -------------------- phasor + split-scan cumsum -> Rg ---------------------
// grid 512 = chunk (0..255) x dim-half (0..1); 256 threads.
// Thread (seg=tid>>7, dp=tid&127) owns dims d0=half*256+dp*2, d0+1.
// 1a: 32-token local phasor-cumsum; seg0 rows -> Rg direct, seg1 rows ->
//     LDS partial P; seg0 totals -> Tr/Ti.
// 1b: all threads fix 16 upper rows each: reload qm/bp (L1/L2-hot),
//     recompute sincos(qp), add seg0-prefix, write Rg.
// Tiny LDS (18 KB) + ~64 VGPR -> multiple blocks/CU -> phases overlap
// across blocks (the round-6/7 monolith had 1 block/CU, phase-serialized).
__global__ __launch_bounds__(256, 4) void phasor_scan(
    const __hip_bfloat16* __restrict__ VKQ,   // [16384,1536] planar
    const float* __restrict__ bp,             // [4096,512]
    const float* __restrict__ mod_scale,
    __hip_bfloat16* __restrict__ Rg) {        // [16384,512] retrieved
  __shared__ __hip_bfloat16 P[32][256];       // partial rows 32..63 (16 KB)
  __shared__ float Tr[256], Ti[256];          // seg0 totals (2 KB)
  const int tid   = threadIdx.x;
  const int seg   = tid >> 7;                 // 0/1 (wave-uniform)
  const int dp    = tid & 127;
  const int dloc  = dp * 2;
  const int chunk = blockIdx.x >> 1;          // 0..255
  const int half  = blockIdx.x & 1;
  const int d0    = half * 256 + dloc;
  const int token0 = chunk * 64;
  const int sg0    = (chunk & (NCHUNK - 1)) * 64;
  const float msc  = mod_scale[0];
  const float isd  = 0.044194173824159216f;   // 1/sqrt(512)

  // ---- 1a: local phasor + cumsum over 32 tokens, 2 dims ----
  {
    const int r0 = seg * 32;
    float mr0 = 0.f, mi0 = 0.f, mr1 = 0.f, mi1 = 0.f;
    const __hip_bfloat16* vb = VKQ + (size_t)(token0 + r0) * 1536 + d0;
    const float* bb = bp + (size_t)(sg0 + r0) * 512 + d0;
#pragma unroll 4
    for (int s = 0; s < 32; ++s) {
      ushort2 v2  = *(const ushort2*)(vb + (size_t)s * 1536);
      ushort2 km2 = *(const ushort2*)(vb + (size_t)s * 1536 + 512);
      ushort2 qm2 = *(const ushort2*)(vb + (size_t)s * 1536 + 1024);
      float2 b2   = *(const float2*)(bb + (size_t)s * 512);
      float v0 = u2f(v2.x), v1 = u2f(v2.y);
      float kp0 = b2.x + u2f(km2.x) * msc;
      float kp1 = b2.y + u2f(km2.y) * msc;
      float qp0 = b2.x + u2f(qm2.x) * msc;
      float qp1 = b2.y + u2f(qm2.y) * msc;
      float sk0, ck0, sk1, ck1, sq0, cq0, sq1, cq1;
      __sincosf(kp0, &sk0, &ck0);
      __sincosf(kp1, &sk1, &ck1);
      __sincosf(qp0, &sq0, &cq0);
      __sincosf(qp1, &sq1, &cq1);
      mr0 += v0 * ck0; mi0 += v0 * sk0;
      mr1 += v1 * ck1; mi1 += v1 * sk1;
      float rr0 = (mr0 * cq0 + mi0 * sq0) * isd;
      float rr1 = (mr1 * cq1 + mi1 * sq1) * isd;
      unsigned int pw = pack2bf(rr0, rr1);
      if (seg == 0)
        *(unsigned int*)(Rg + (size_t)(token0 + s) * 512 + d0) = pw;
      else
        *(unsigned int*)(&P[s][dloc]) = pw;
    }
    if (seg == 0) {
      Tr[dloc] = mr0; Tr[dloc + 1] = mr1;
      Ti[dloc] = mi0; Ti[dloc + 1] = mi1;
    }
  }
  __syncthreads();

  // ---- 1b: fix rows 32..63 (16 rows/thread) with seg0 prefix ----
  {
    const float pr0 = Tr[dloc] * isd,     pi0 = Ti[dloc] * isd;
    const float pr1 = Tr[dloc + 1] * isd, pi1 = Ti[dloc + 1] * isd;
    const int rf = 32 + seg * 16;
    const __hip_bfloat16* qb = VKQ + (size_t)(token0 + rf) * 1536 + 1024 + d0;
    const float* bb = bp + (size_t)(sg0 + rf) * 512 + d0;
#pragma unroll 4
    for (int s = 0; s < 16; ++s) {
      ushort2 qm2 = *(const ushort2*)(qb + (size_t)s * 1536);
      float2 b2   = *(const float2*)(bb + (size_t)s * 512);
      float qp0 = b2.x + u2f(qm2.x) * msc;
      float qp1 = b2.y + u2f(qm2.y) * msc;
      float sq0, cq0, sq1, cq1;
      __sincosf(qp0, &sq0, &cq0);
      __sincosf(qp1, &sq1, &cq1);
      unsigned int old = *(unsigned int*)(&P[rf - 32 + s][dloc]);
      float a = u2f((unsigned short)(old & 0xffffu)) + pr0 * cq0 + pi0 * sq0;
      float b = u2f((unsigned short)(old >> 16))     + pr1 * cq1 + pi1 * sq1;
      *(unsigned int*)(Rg + (size_t)(token0 + rf + s) * 512 + d0) =
          pack2bf(a, b);
    }
  }
}

// ------------------- LN + GEMM(Wo) + bias + residual -----------------------
// grid 512 (32 rows each), 256 threads (4 waves), 33 KB LDS -> 4 blocks/CU.
// LN: wave wv rows wv*8..+7, lane holds 8 contiguous dims (short8 load).
// GEMM: wave wv cols wv*128..+127, acc[2][8]; Wo stays L2-resident.
__global__ __launch_bounds__(256, 4) void ln_gemm(
    const __hip_bfloat16* __restrict__ Rg,    // [16384,512] retrieved bf16
    const float* __restrict__ ln_g, const float* __restrict__ ln_b,
    const __hip_bfloat16* __restrict__ WoB,   // [512,512] bf16
    const float* __restrict__ bo,
    const float* __restrict__ x,              // resid f32
    float* __restrict__ out) {
  __shared__ __align__(16) __hip_bfloat16 Ns[32 * NSPAD];   // 32.5 KB
  const int tid  = threadIdx.x;
  const int lane = tid & 63;
  const int wv   = tid >> 6;                  // 0..3
  const int row0 = blockIdx.x * 32;

  // ---- LN: 8 rows per wave ----
  {
    float4 g0 = *(const float4*)(ln_g + lane * 8);
    float4 g1 = *(const float4*)(ln_g + lane * 8 + 4);
    float4 c0 = *(const float4*)(ln_b + lane * 8);
    float4 c1 = *(const float4*)(ln_b + lane * 8 + 4);
    float gj[8] = {g0.x, g0.y, g0.z, g0.w, g1.x, g1.y, g1.z, g1.w};
    float bj[8] = {c0.x, c0.y, c0.z, c0.w, c1.x, c1.y, c1.z, c1.w};
    for (int rr = 0; rr < 8; ++rr) {
      int row = wv * 8 + rr;
      short8 v8 = *(const short8*)(Rg + (size_t)(row0 + row) * 512 + lane * 8);
      float vals[8], sum = 0.f, sq2 = 0.f;
#pragma unroll
      for (int j = 0; j < 8; j++) {
        float v = u2f((unsigned short)v8[j]);
        vals[j] = v;
        sum += v;
        sq2 += v * v;
      }
#pragma unroll
      for (int off = 32; off; off >>= 1) {
        sum += __shfl_xor(sum, off, 64);
        sq2 += __shfl_xor(sq2, off, 64);
      }
      float mu   = sum * (1.f / 512.f);
      float var  = sq2 * (1.f / 512.f) - mu * mu;
      float rstd = rsqrtf(var + 1e-5f);
      short8 n8;
#pragma unroll
      for (int j = 0; j < 8; j++) {
        union { __hip_bfloat16 h; unsigned short s; } cv;
        cv.h = __float2bfloat16((vals[j] - mu) * rstd * gj[j] + bj[j]);
        n8[j] = (short)cv.s;
      }
      *(short8*)(Ns + row * NSPAD + lane * 8) = n8;
    }
  }
  __syncthreads();

  // ---- GEMM: C(32x512) = Ns @ WoB^T + bo + x -> out ----
  {
    const int rfA = lane & 15;
    const int rfK = (lane >> 4) * 8;
    f32x4 acc[2][8] = {};

    for (int kt = 0; kt < 512; kt += 32) {
      short8 af0 = *(const short8*)(Ns + (rfA) * NSPAD + kt + rfK);
      short8 af1 = *(const short8*)(Ns + (16 + rfA) * NSPAD + kt + rfK);
#pragma unroll
      for (int j = 0; j < 8; ++j) {
        short8 bf8 = *(const short8*)(
            WoB + (size_t)(wv * 128 + j * 16 + rfA) * 512 + kt + rfK);
        acc[0][j] = __builtin_amdgcn_mfma_f32_16x16x32_bf16(
            af0, bf8, acc[0][j], 0, 0, 0);
        acc[1][j] = __builtin_amdgcn_mfma_f32_16x16x32_bf16(
            af1, bf8, acc[1][j], 0, 0, 0);
      }
    }

    const int cq = lane >> 4;
    float bz[8];
#pragma unroll
    for (int j = 0; j < 8; j++) bz[j] = bo[wv * 128 + j * 16 + (lane & 15)];
#pragma unroll
    for (int i = 0; i < 2; i++) {
      int row = row0 + i * 16 + cq * 4;
#pragma unroll
      for (int j = 0; j < 8; j++) {
        int col = wv * 128 + j * 16 + (lane & 15);
#pragma unroll
        for (int r = 0; r < 4; r++) {
          size_t o = (size_t)(row + r) * 512 + col;
          out[o] = acc[i][j][r] + bz[j] + x[o];
        }
      }
    }
  }
}

// ------------------------------- launcher ----------------------------------
extern "C" void kernel_launch(void* const* d_in, const int* in_sizes, int n_in,
                              void* d_out, int out_size, void* d_ws,
                              size_t ws_size, hipStream_t stream) {
  const float* x    = (const float*)d_in[0];
  const float* bp   = (const float*)d_in[1];
  const float* Wk   = (const float*)d_in[2];
  const float* bk   = (const float*)d_in[3];
  const float* Wv   = (const float*)d_in[4];
  const float* bv   = (const float*)d_in[5];
  const float* Wq   = (const float*)d_in[6];
  const float* bq   = (const float*)d_in[7];
  const float* Wkm  = (const float*)d_in[8];
  const float* bkm  = (const float*)d_in[9];
  const float* Wqm  = (const float*)d_in[10];
  const float* bqm  = (const float*)d_in[11];
  const float* msc  = (const float*)d_in[12];
  const float* lng  = (const float*)d_in[13];
  const float* lnb  = (const float*)d_in[14];
  const float* Wo   = (const float*)d_in[15];
  const float* bo   = (const float*)d_in[16];
  float* out = (float*)d_out;

  char* ws = (char*)d_ws;
  __hip_bfloat16* x_bf  = (__hip_bfloat16*)ws;  ws += (size_t)M_TOK * DIM * 2;
  __hip_bfloat16* Wall  = (__hip_bfloat16*)ws;  ws += (size_t)2048 * 512 * 2;
  __hip_bfloat16* Wm_bf = (__hip_bfloat16*)ws;  ws += (size_t)2 * 262144 * 2;
  __hip_bfloat16* WT_bf = (__hip_bfloat16*)ws;  ws += (size_t)2 * 262144 * 2;
  float*          bc1   = (float*)ws;           ws += 1536 * 4;
  __hip_bfloat16* VKQ   = (__hip_bfloat16*)ws;  ws += (size_t)M_TOK * 1536 * 2;
  // Rg reuses x_bf: x_bf is dead after gemm_bt, sizes match exactly (16 MB)
  __hip_bfloat16* Rg = x_bf;

  // 1) merged prep: cvt x + pack/cvt/transpose weights + compose biases
  prep_all<<<9600, 256, 0, stream>>>(x, x_bf, Wv, Wo, bv, Wkm, Wqm, Wk, Wq,
                                     bk, bkm, bq, bqm, Wall, bc1, Wm_bf,
                                     WT_bf);
  // 2) MFMA compose: Wkk, Wqq -> Wall rows 512..1535
  gemm_compose<<<dim3(4, 4, 2), 256, 0, stream>>>(Wm_bf, WT_bf, Wall);
  // 3) VKQ = x @ [Wv|Wkk|Wqq]^T + bias, planar [16384,1536]
  gemm_bt<<<dim3(1536), 256, 0, stream>>>(x_bf, DIM, Wall, bc1, VKQ, 1536);
  // 4) phasor + split-scan cumsum -> Rg (bf16)
  phasor_scan<<<512, 256, 0, stream>>>(VKQ, bp, msc, Rg);
  // 5) LN + GEMM(Wo) + bo + resid -> out
  ln_gemm<<<512, 256, 0, stream>>>(Rg, lng, lnb, Wall + (size_t)1536 * 512,
                                   bo, x, out);
}

// Round 3
// 206.564 us; speedup vs baseline: 1.2179x; 1.2179x over previous
//
#include <hip/hip_runtime.h>
#include <hip/hip_bf16.h>

// ---------------------------------------------------------------------------
// OrthoInitPhasor round 9
//   prep_all:     cvt x->bf16, pack Wv/Wo, cvt Wkm/Wqm, transpose Wk/Wq,
//                 compose biases
//   gemm_compose: Wkk = Wkm@Wk, Wqq = Wqm@Wq via MFMA
//   gemm_bt:      x @ [Wv|Wkk|Wqq]^T + bias -> VKQ planar [16384,1536] bf16
//                 XCD-swizzled grid + TRUE double-buffered staging
//                 (T3-minimum: stage(next) issued before MFMA(cur),
//                 one barrier per K-tile -> load latency hidden)
//   fused_pg:     round-6 proven monolith: 1024-thr 2-segment split-scan
//                 phasor+cumsum+LN + MFMA GEMM vs Wo + resid -> out
// ---------------------------------------------------------------------------

typedef __attribute__((ext_vector_type(8))) short short8;   // 8 x bf16
typedef __attribute__((ext_vector_type(4))) float f32x4;

#define M_TOK   16384
#define DIM     512
#define NCHUNK  64
#define RPAD    520   // LDS row stride (bf16 elems) for normed tile

__device__ __forceinline__ void gll16(const void* g, void* l) {
  __builtin_amdgcn_global_load_lds(
      (const __attribute__((address_space(1))) unsigned int*)g,
      (__attribute__((address_space(3))) unsigned int*)l, 16, 0, 0);
}

__device__ __forceinline__ uint2 pack4bf(float4 v) {
  union { __hip_bfloat16 h[4]; uint2 u; } t;
  t.h[0] = __float2bfloat16(v.x);
  t.h[1] = __float2bfloat16(v.y);
  t.h[2] = __float2bfloat16(v.z);
  t.h[3] = __float2bfloat16(v.w);
  return t.u;
}

// ------------------------------ prep (merged) ------------------------------
__global__ __launch_bounds__(256) void prep_all(
    const float* __restrict__ x, __hip_bfloat16* __restrict__ x_bf,
    const float* __restrict__ Wv, const float* __restrict__ Wo,
    const float* __restrict__ bv,
    const float* __restrict__ Wkm, const float* __restrict__ Wqm,
    const float* __restrict__ Wk, const float* __restrict__ Wq,
    const float* __restrict__ bk, const float* __restrict__ bkm,
    const float* __restrict__ bq, const float* __restrict__ bqm,
    __hip_bfloat16* __restrict__ Wall, float* __restrict__ bc1,
    __hip_bfloat16* __restrict__ Wm_bf, __hip_bfloat16* __restrict__ WT_bf) {
  const int tid = threadIdx.x;
  if (blockIdx.x < 8192) {
    int i = blockIdx.x * 256 + tid;          // 2097152 float4s
    ((uint2*)x_bf)[i] = pack4bf(((const float4*)x)[i]);
    return;
  }
  const int b = blockIdx.x - 8192;
  if (b < 512) {
    int m = b >> 8;
    int idx = ((b & 255) * 256 + tid) * 4;
    const float* src = m ? Wo : Wv;
    __hip_bfloat16* dst = Wall + (m ? (size_t)1536 * 512 : 0);
    ((uint2*)dst)[idx >> 2] = pack4bf(*(const float4*)(src + idx));
    int t = b * 256 + tid;
    if (t < 512) bc1[t] = bv[t];
  } else if (b < 1024) {
    int bb = b - 512;
    int m = bb >> 8;
    int idx = ((bb & 255) * 256 + tid) * 4;
    const float* src = m ? Wqm : Wkm;
    ((uint2*)(Wm_bf + (size_t)m * 262144))[idx >> 2] =
        pack4bf(*(const float4*)(src + idx));
  } else if (b < 1152) {
    __shared__ float tile[64][65];
    int bb = b - 1024;
    int z = bb >> 6;
    int tl = bb & 63;
    int tr = tl >> 3, tc = tl & 7;
    const float* src = z ? Wq : Wk;
#pragma unroll
    for (int i = 0; i < 4; i++) {
      int r = (tid >> 4) + 16 * i;
      int c4 = (tid & 15) * 4;
      float4 v = *(const float4*)(src + (size_t)(tr * 64 + r) * 512 +
                                  tc * 64 + c4);
      tile[r][c4 + 0] = v.x;
      tile[r][c4 + 1] = v.y;
      tile[r][c4 + 2] = v.z;
      tile[r][c4 + 3] = v.w;
    }
    __syncthreads();
    int orow = tid >> 2;
    int seg = tid & 3;
    __hip_bfloat16* dst = WT_bf + (size_t)z * 262144 +
                          (size_t)(tc * 64 + orow) * 512 + tr * 64 + seg * 16;
#pragma unroll
    for (int q = 0; q < 4; q++) {
      float4 v;
      v.x = tile[seg * 16 + q * 4 + 0][orow];
      v.y = tile[seg * 16 + q * 4 + 1][orow];
      v.z = tile[seg * 16 + q * 4 + 2][orow];
      v.w = tile[seg * 16 + q * 4 + 3][orow];
      *(uint2*)(dst + q * 4) = pack4bf(v);
    }
  } else {
    int row = (b - 1152) * 4 + (tid >> 6);
    int lane = tid & 63;
    int z = row >> 9;
    int i = row & 511;
    const float* Wm = z ? Wqm : Wkm;
    const float* b0 = z ? bq : bk;
    const float* bm = z ? bqm : bkm;
    const float4* w4 = (const float4*)(Wm + (size_t)i * 512 + lane * 8);
    const float4* v4 = (const float4*)(b0 + lane * 8);
    float4 w0 = w4[0], w1 = w4[1], c0 = v4[0], c1 = v4[1];
    float acc = w0.x * c0.x + w0.y * c0.y + w0.z * c0.z + w0.w * c0.w +
                w1.x * c1.x + w1.y * c1.y + w1.z * c1.z + w1.w * c1.w;
#pragma unroll
    for (int off = 32; off; off >>= 1) acc += __shfl_xor(acc, off, 64);
    if (lane == 0) bc1[512 + z * 512 + i] = acc + bm[i];
  }
}

// ------------------------------- GEMM (B^T) --------------------------------
// C[m,n] = sum_k A[m,k] * Bt[n,k] + bias[n], bf16 planar store (ldc)
// 1D grid 1536, XCD-swizzled so each XCD owns contiguous M-panels.
// TRUE double-buffer: stage(next K-tile) issued before MFMA(cur K-tile);
// one barrier per tile. Loads stay in flight under the MFMA block.
__global__ __launch_bounds__(256) void gemm_bt(
    const __hip_bfloat16* __restrict__ A, int lda,
    const __hip_bfloat16* __restrict__ Bt,
    const float* __restrict__ bias,
    __hip_bfloat16* __restrict__ Cout, int ldc) {
  constexpr int K = 512, BK = 32;
  __shared__ __align__(16) __hip_bfloat16 As[2][128 * BK];   // 2 x 8 KB
  __shared__ __align__(16) __hip_bfloat16 Bs[2][128 * BK];   // 2 x 8 KB

  const int tid  = threadIdx.x;
  const int lane = tid & 63;
  const int w    = tid >> 6;
  const int wm   = w >> 1;
  const int wn   = w & 1;
  // bijective XCD swizzle: nwg=1536=8*192
  const int lb = (blockIdx.x & 7) * 192 + (blockIdx.x >> 3);
  const int by = lb / 12;
  const int bx = lb - by * 12;
  const int m0 = by * 128;
  const int n0 = bx * 128;

  const int rS0    = (w * 2 + 0) * 16 + (lane >> 2);
  const int rS1    = (w * 2 + 1) * 16 + (lane >> 2);
  const int kInRow = (lane & 3) * 8;
  const __hip_bfloat16* gA0 = A + (size_t)(m0 + rS0) * lda + kInRow;
  const __hip_bfloat16* gA1 = A + (size_t)(m0 + rS1) * lda + kInRow;
  const __hip_bfloat16* gB0 = Bt + (size_t)(n0 + rS0) * K + kInRow;
  const __hip_bfloat16* gB1 = Bt + (size_t)(n0 + rS1) * K + kInRow;
  char* ldsA0 = (char*)&As[0][0] + (w * 2 + 0) * 1024;
  char* ldsA1 = (char*)&As[0][0] + (w * 2 + 1) * 1024;
  char* ldsB0 = (char*)&Bs[0][0] + (w * 2 + 0) * 1024;
  char* ldsB1 = (char*)&Bs[0][0] + (w * 2 + 1) * 1024;

  f32x4 acc[4][4] = {};

  const int rfA = lane & 15;
  const int rfK = (lane >> 4) * 8;

  // prologue: stage K-tile 0 into buf 0
  gll16(gA0, ldsA0);
  gll16(gA1, ldsA1);
  gll16(gB0, ldsB0);
  gll16(gB1, ldsB1);

#pragma unroll 2
  for (int kt = 0; kt < K; kt += BK) {
    const int cur = (kt >> 5) & 1;          // buffer holding tile kt
    const int coff = cur * 8192;            // byte offset of cur buffer
    __syncthreads();                        // tile kt staged; prev reads done
    const int nxt = kt + BK;
    if (nxt < K) {
      const int noff = 8192 - coff;
      gll16(gA0 + nxt, ldsA0 + noff);
      gll16(gA1 + nxt, ldsA1 + noff);
      gll16(gB0 + nxt, ldsB0 + noff);
      gll16(gB1 + nxt, ldsB1 + noff);
    }
    const __hip_bfloat16* Ah = &As[cur][0];
    const __hip_bfloat16* Bh = &Bs[cur][0];
    short8 af[4], bfv[4];
#pragma unroll
    for (int i = 0; i < 4; i++)
      af[i] = *(const short8*)(Ah + (wm * 64 + i * 16 + rfA) * BK + rfK);
#pragma unroll
    for (int j = 0; j < 4; j++)
      bfv[j] = *(const short8*)(Bh + (wn * 64 + j * 16 + rfA) * BK + rfK);
#pragma unroll
    for (int i = 0; i < 4; i++)
#pragma unroll
      for (int j = 0; j < 4; j++)
        acc[i][j] = __builtin_amdgcn_mfma_f32_16x16x32_bf16(
            af[i], bfv[j], acc[i][j], 0, 0, 0);
  }

  const int cq = lane >> 4;
#pragma unroll
  for (int i = 0; i < 4; i++) {
    int row = m0 + wm * 64 + i * 16 + cq * 4;
#pragma unroll
    for (int j = 0; j < 4; j++) {
      int col = n0 + wn * 64 + j * 16 + (lane & 15);
      float bz = bias[col];
#pragma unroll
      for (int r = 0; r < 4; r++) {
        float v = acc[i][j][r] + bz;
        Cout[(size_t)(row + r) * ldc + col] = __float2bfloat16(v);
      }
    }
  }
}

// --------------- compose GEMM: Wkk=Wkm@Wk, Wqq=Wqm@Wq (MFMA) ---------------
__global__ __launch_bounds__(256) void gemm_compose(
    const __hip_bfloat16* __restrict__ Wm_bf,
    const __hip_bfloat16* __restrict__ WT_bf,
    __hip_bfloat16* __restrict__ Wall) {
  constexpr int K = 512, BK = 32;
  const __hip_bfloat16* A  = Wm_bf + (size_t)blockIdx.z * 262144;
  const __hip_bfloat16* Bt = WT_bf + (size_t)blockIdx.z * 262144;
  __hip_bfloat16* C = Wall + (size_t)(512 + blockIdx.z * 512) * 512;
  __shared__ __align__(16) __hip_bfloat16 As[128 * BK];
  __shared__ __align__(16) __hip_bfloat16 Bs[128 * BK];

  const int tid  = threadIdx.x;
  const int lane = tid & 63;
  const int w    = tid >> 6;
  const int wm   = w >> 1;
  const int wn   = w & 1;
  const int m0   = blockIdx.y * 128;
  const int n0   = blockIdx.x * 128;

  const int rS0    = (w * 2 + 0) * 16 + (lane >> 2);
  const int rS1    = (w * 2 + 1) * 16 + (lane >> 2);
  const int kInRow = (lane & 3) * 8;
  const __hip_bfloat16* gA0 = A + (size_t)(m0 + rS0) * K + kInRow;
  const __hip_bfloat16* gA1 = A + (size_t)(m0 + rS1) * K + kInRow;
  const __hip_bfloat16* gB0 = Bt + (size_t)(n0 + rS0) * K + kInRow;
  const __hip_bfloat16* gB1 = Bt + (size_t)(n0 + rS1) * K + kInRow;
  char* ldsA0 = (char*)As + (w * 2 + 0) * 1024;
  char* ldsA1 = (char*)As + (w * 2 + 1) * 1024;
  char* ldsB0 = (char*)Bs + (w * 2 + 0) * 1024;
  char* ldsB1 = (char*)Bs + (w * 2 + 1) * 1024;

  f32x4 acc[4][4] = {};
  const int rfA = lane & 15;
  const int rfK = (lane >> 4) * 8;

  for (int kt = 0; kt < K; kt += BK) {
    __syncthreads();
    gll16(gA0 + kt, ldsA0);
    gll16(gA1 + kt, ldsA1);
    gll16(gB0 + kt, ldsB0);
    gll16(gB1 + kt, ldsB1);
    __syncthreads();

    short8 af[4], bf[4];
#pragma unroll
    for (int i = 0; i < 4; i++)
      af[i] = *(const short8*)(As + (wm * 64 + i * 16 + rfA) * BK + rfK);
#pragma unroll
    for (int j = 0; j < 4; j++)
      bf[j] = *(const short8*)(Bs + (wn * 64 + j * 16 + rfA) * BK + rfK);
#pragma unroll
    for (int i = 0; i < 4; i++)
#pragma unroll
      for (int j = 0; j < 4; j++)
        acc[i][j] = __builtin_amdgcn_mfma_f32_16x16x32_bf16(
            af[i], bf[j], acc[i][j], 0, 0, 0);
  }

  const int cq = lane >> 4;
#pragma unroll
  for (int i = 0; i < 4; i++) {
    int row = m0 + wm * 64 + i * 16 + cq * 4;
#pragma unroll
    for (int j = 0; j < 4; j++) {
      int col = n0 + wn * 64 + j * 16 + (lane & 15);
#pragma unroll
      for (int r = 0; r < 4; r++)
        C[(size_t)(row + r) * 512 + col] = __float2bfloat16(acc[i][j][r]);
    }
  }
}

// ------ fused: phasor + split-scan cumsum + LN + GEMM(Wo) + resid ----------
// grid 256 (= B*nC), 1024 threads (16 waves). One chunk (64 tokens) / block.
// (round-6 proven version: 45.8 us, VGPR 44)
__global__ __launch_bounds__(1024) void fused_pg(
    const __hip_bfloat16* __restrict__ VKQ,   // [16384,1536] planar
    const float* __restrict__ bp,             // [4096,512]
    const float* __restrict__ mod_scale,
    const float* __restrict__ ln_g, const float* __restrict__ ln_b,
    const __hip_bfloat16* __restrict__ WoB,   // [512,512] bf16
    const float* __restrict__ bo,
    const float* __restrict__ x,              // resid f32
    float* __restrict__ out) {
  __shared__ __hip_bfloat16 R[64 * RPAD];     // 66.5 KB
  __shared__ float Tr[512], Ti[512];          // seg0 complex totals
  const int tid    = threadIdx.x;
  const int seg    = tid >> 9;                // 0 or 1
  const int d      = tid & 511;
  const int blk    = blockIdx.x;
  const int token0 = blk * 64;
  const int sg0    = (blk & (NCHUNK - 1)) * 64;
  const float msc  = mod_scale[0];
  const float isd  = 0.044194173824159216f;   // 1/sqrt(512)

  // ---- phase 1a: per-segment local phasor + cumsum (32 tokens) ----
  {
    const int s0 = seg * 32;
    float mr = 0.f, mi = 0.f;
    const __hip_bfloat16* vb = VKQ + (size_t)(token0 + s0) * 1536 + d;
    const float* bb = bp + (size_t)(sg0 + s0) * 512 + d;
#pragma unroll 4
    for (int s = 0; s < 32; ++s) {
      float v  = __bfloat162float(vb[(size_t)s * 1536]);
      float km = __bfloat162float(vb[(size_t)s * 1536 + 512]);
      float qm = __bfloat162float(vb[(size_t)s * 1536 + 1024]);
      float b  = bb[(size_t)s * 512];
      float kp = b + km * msc;
      float qp = b + qm * msc;
      float sk, ck, sq, cq;
      __sincosf(kp, &sk, &ck);
      __sincosf(qp, &sq, &cq);
      mr += v * ck;
      mi += v * sk;
      R[(s0 + s) * RPAD + d] = __float2bfloat16((mr * cq + mi * sq) * isd);
    }
    if (seg == 0) {
      Tr[d] = mr;
      Ti[d] = mi;
    }
  }
  __syncthreads();

  // ---- phase 1b: fixup rows 32..63 with seg0 prefix (all 1024 threads) ----
  {
    const int r0 = 32 + seg * 16;             // 16 rows per thread-half
    const float pr = Tr[d] * isd;
    const float pi = Ti[d] * isd;
    const __hip_bfloat16* qb = VKQ + (size_t)(token0 + r0) * 1536 + 1024 + d;
    const float* bb = bp + (size_t)(sg0 + r0) * 512 + d;
#pragma unroll 4
    for (int s = 0; s < 16; ++s) {
      float qm = __bfloat162float(qb[(size_t)s * 1536]);
      float b  = bb[(size_t)s * 512];
      float qp = b + qm * msc;
      float sq, cq;
      __sincosf(qp, &sq, &cq);
      int idx = (r0 + s) * RPAD + d;
      float v = __bfloat162float(R[idx]) + pr * cq + pi * sq;
      R[idx] = __float2bfloat16(v);
    }
  }
  __syncthreads();

  // ---- LayerNorm in place (wave wv owns rows wv*4..+3) ----
  {
    const int lane = tid & 63;
    const int wv   = tid >> 6;                // 0..15
    float gj[8], bj[8];
#pragma unroll
    for (int j = 0; j < 8; j++) {
      int col = lane + 64 * j;
      gj[j] = ln_g[col];
      bj[j] = ln_b[col];
    }
    for (int rr = 0; rr < 4; ++rr) {
      int row = wv * 4 + rr;
      float vals[8], sum = 0.f, sq2 = 0.f;
#pragma unroll
      for (int j = 0; j < 8; j++) {
        float v = __bfloat162float(R[row * RPAD + lane + 64 * j]);
        vals[j] = v;
        sum += v;
        sq2 += v * v;
      }
#pragma unroll
      for (int off = 32; off; off >>= 1) {
        sum += __shfl_xor(sum, off, 64);
        sq2 += __shfl_xor(sq2, off, 64);
      }
      float mu   = sum * (1.f / 512.f);
      float var  = sq2 * (1.f / 512.f) - mu * mu;
      float rstd = rsqrtf(var + 1e-5f);
#pragma unroll
      for (int j = 0; j < 8; j++) {
        float nv = (vals[j] - mu) * rstd * gj[j] + bj[j];
        R[row * RPAD + lane + 64 * j] = __float2bfloat16(nv);
      }
    }
  }
  __syncthreads();

  // ---- phase 2: C(64x512) = R @ WoB^T + bo + x -> out (16 waves) ----
  {
    const int lane = tid & 63;
    const int w    = tid >> 6;                // wave 0..15 -> cols w*32..+31
    const int rfA  = lane & 15;
    const int rfK  = (lane >> 4) * 8;
    f32x4 acc[4][2] = {};

    for (int kt = 0; kt < 512; kt += 32) {
      short8 af[4], bf[2];
#pragma unroll
      for (int j = 0; j < 2; j++) {
        int col = w * 32 + j * 16 + rfA;
        bf[j] = *(const short8*)(WoB + (size_t)col * 512 + kt + rfK);
      }
#pragma unroll
      for (int i = 0; i < 4; i++)
        af[i] = *(const short8*)(R + (i * 16 + rfA) * RPAD + kt + rfK);
#pragma unroll
      for (int i = 0; i < 4; i++)
#pragma unroll
        for (int j = 0; j < 2; j++)
          acc[i][j] = __builtin_amdgcn_mfma_f32_16x16x32_bf16(
              af[i], bf[j], acc[i][j], 0, 0, 0);
    }

    const int cq = lane >> 4;
    float bz[2];
#pragma unroll
    for (int j = 0; j < 2; j++) bz[j] = bo[w * 32 + j * 16 + (lane & 15)];
#pragma unroll
    for (int i = 0; i < 4; i++) {
      int row = token0 + i * 16 + cq * 4;
#pragma unroll
      for (int j = 0; j < 2; j++) {
        int col = w * 32 + j * 16 + (lane & 15);
#pragma unroll
        for (int r = 0; r < 4; r++) {
          size_t o = (size_t)(row + r) * 512 + col;
          out[o] = acc[i][j][r] + bz[j] + x[o];
        }
      }
    }
  }
}

// ------------------------------- launcher ----------------------------------
extern "C" void kernel_launch(void* const* d_in, const int* in_sizes, int n_in,
                              void* d_out, int out_size, void* d_ws,
                              size_t ws_size, hipStream_t stream) {
  const float* x    = (const float*)d_in[0];
  const float* bp   = (const float*)d_in[1];
  const float* Wk   = (const float*)d_in[2];
  const float* bk   = (const float*)d_in[3];
  const float* Wv   = (const float*)d_in[4];
  const float* bv   = (const float*)d_in[5];
  const float* Wq   = (const float*)d_in[6];
  const float* bq   = (const float*)d_in[7];
  const float* Wkm  = (const float*)d_in[8];
  const float* bkm  = (const float*)d_in[9];
  const float* Wqm  = (const float*)d_in[10];
  const float* bqm  = (const float*)d_in[11];
  const float* msc  = (const float*)d_in[12];
  const float* lng  = (const float*)d_in[13];
  const float* lnb  = (const float*)d_in[14];
  const float* Wo   = (const float*)d_in[15];
  const float* bo   = (const float*)d_in[16];
  float* out = (float*)d_out;

  char* ws = (char*)d_ws;
  __hip_bfloat16* x_bf  = (__hip_bfloat16*)ws;  ws += (size_t)M_TOK * DIM * 2;
  __hip_bfloat16* Wall  = (__hip_bfloat16*)ws;  ws += (size_t)2048 * 512 * 2;
  __hip_bfloat16* Wm_bf = (__hip_bfloat16*)ws;  ws += (size_t)2 * 262144 * 2;
  __hip_bfloat16* WT_bf = (__hip_bfloat16*)ws;  ws += (size_t)2 * 262144 * 2;
  float*          bc1   = (float*)ws;           ws += 1536 * 4;
  __hip_bfloat16* VKQ   = (__hip_bfloat16*)ws;  ws += (size_t)M_TOK * 1536 * 2;

  // 1) merged prep: cvt x + pack/cvt/transpose weights + compose biases
  prep_all<<<9600, 256, 0, stream>>>(x, x_bf, Wv, Wo, bv, Wkm, Wqm, Wk, Wq,
                                     bk, bkm, bq, bqm, Wall, bc1, Wm_bf,
                                     WT_bf);
  // 2) MFMA compose: Wkk, Wqq -> Wall rows 512..1535
  gemm_compose<<<dim3(4, 4, 2), 256, 0, stream>>>(Wm_bf, WT_bf, Wall);
  // 3) VKQ = x @ [Wv|Wkk|Wqq]^T + bias, planar [16384,1536]
  gemm_bt<<<dim3(1536), 256, 0, stream>>>(x_bf, DIM, Wall, bc1, VKQ, 1536);
  // 4) fused phasor + split-scan cumsum + LN + GEMM(Wo) + bo + resid -> out
  fused_pg<<<256, 1024, 0, stream>>>(VKQ, bp, msc, lng, lnb,
                                     Wall + (size_t)1536 * 512, bo, x, out);
}

// Round 4
// 202.978 us; speedup vs baseline: 1.2394x; 1.0177x over previous
//
#include <hip/hip_runtime.h>
#include <hip/hip_bf16.h>

// ---------------------------------------------------------------------------
// OrthoInitPhasor round 10 — combine proven-best pieces
//   prep_all:     cvt x->bf16, pack Wv/Wo, cvt Wkm/Wqm, transpose Wk/Wq,
//                 compose biases
//   gemm_compose: Wkk = Wkm@Wk, Wqq = Wqm@Wq via MFMA
//   gemm_bt:      x @ [Wv|Wkk|Wqq]^T + bias -> VKQ planar [16384,1536] bf16
//                 r1-proven: XCD-swizzled grid + 2 K-slices per barrier pair
//                 (static LDS offsets, 8 drain points total)
//   fused_pg:     r6-proven monolith (45.8 us, VGPR 44): 1024-thr 2-segment
//                 split-scan phasor+cumsum+LN + MFMA GEMM(Wo) + resid
// ---------------------------------------------------------------------------

typedef __attribute__((ext_vector_type(8))) short short8;   // 8 x bf16
typedef __attribute__((ext_vector_type(4))) float f32x4;

#define M_TOK   16384
#define DIM     512
#define NCHUNK  64
#define RPAD    520   // LDS row stride (bf16 elems) for normed tile

__device__ __forceinline__ void gll16(const void* g, void* l) {
  __builtin_amdgcn_global_load_lds(
      (const __attribute__((address_space(1))) unsigned int*)g,
      (__attribute__((address_space(3))) unsigned int*)l, 16, 0, 0);
}

__device__ __forceinline__ uint2 pack4bf(float4 v) {
  union { __hip_bfloat16 h[4]; uint2 u; } t;
  t.h[0] = __float2bfloat16(v.x);
  t.h[1] = __float2bfloat16(v.y);
  t.h[2] = __float2bfloat16(v.z);
  t.h[3] = __float2bfloat16(v.w);
  return t.u;
}

// ------------------------------ prep (merged) ------------------------------
__global__ __launch_bounds__(256) void prep_all(
    const float* __restrict__ x, __hip_bfloat16* __restrict__ x_bf,
    const float* __restrict__ Wv, const float* __restrict__ Wo,
    const float* __restrict__ bv,
    const float* __restrict__ Wkm, const float* __restrict__ Wqm,
    const float* __restrict__ Wk, const float* __restrict__ Wq,
    const float* __restrict__ bk, const float* __restrict__ bkm,
    const float* __restrict__ bq, const float* __restrict__ bqm,
    __hip_bfloat16* __restrict__ Wall, float* __restrict__ bc1,
    __hip_bfloat16* __restrict__ Wm_bf, __hip_bfloat16* __restrict__ WT_bf) {
  const int tid = threadIdx.x;
  if (blockIdx.x < 8192) {
    int i = blockIdx.x * 256 + tid;          // 2097152 float4s
    ((uint2*)x_bf)[i] = pack4bf(((const float4*)x)[i]);
    return;
  }
  const int b = blockIdx.x - 8192;
  if (b < 512) {
    int m = b >> 8;
    int idx = ((b & 255) * 256 + tid) * 4;
    const float* src = m ? Wo : Wv;
    __hip_bfloat16* dst = Wall + (m ? (size_t)1536 * 512 : 0);
    ((uint2*)dst)[idx >> 2] = pack4bf(*(const float4*)(src + idx));
    int t = b * 256 + tid;
    if (t < 512) bc1[t] = bv[t];
  } else if (b < 1024) {
    int bb = b - 512;
    int m = bb >> 8;
    int idx = ((bb & 255) * 256 + tid) * 4;
    const float* src = m ? Wqm : Wkm;
    ((uint2*)(Wm_bf + (size_t)m * 262144))[idx >> 2] =
        pack4bf(*(const float4*)(src + idx));
  } else if (b < 1152) {
    __shared__ float tile[64][65];
    int bb = b - 1024;
    int z = bb >> 6;
    int tl = bb & 63;
    int tr = tl >> 3, tc = tl & 7;
    const float* src = z ? Wq : Wk;
#pragma unroll
    for (int i = 0; i < 4; i++) {
      int r = (tid >> 4) + 16 * i;
      int c4 = (tid & 15) * 4;
      float4 v = *(const float4*)(src + (size_t)(tr * 64 + r) * 512 +
                                  tc * 64 + c4);
      tile[r][c4 + 0] = v.x;
      tile[r][c4 + 1] = v.y;
      tile[r][c4 + 2] = v.z;
      tile[r][c4 + 3] = v.w;
    }
    __syncthreads();
    int orow = tid >> 2;
    int seg = tid & 3;
    __hip_bfloat16* dst = WT_bf + (size_t)z * 262144 +
                          (size_t)(tc * 64 + orow) * 512 + tr * 64 + seg * 16;
#pragma unroll
    for (int q = 0; q < 4; q++) {
      float4 v;
      v.x = tile[seg * 16 + q * 4 + 0][orow];
      v.y = tile[seg * 16 + q * 4 + 1][orow];
      v.z = tile[seg * 16 + q * 4 + 2][orow];
      v.w = tile[seg * 16 + q * 4 + 3][orow];
      *(uint2*)(dst + q * 4) = pack4bf(v);
    }
  } else {
    int row = (b - 1152) * 4 + (tid >> 6);
    int lane = tid & 63;
    int z = row >> 9;
    int i = row & 511;
    const float* Wm = z ? Wqm : Wkm;
    const float* b0 = z ? bq : bk;
    const float* bm = z ? bqm : bkm;
    const float4* w4 = (const float4*)(Wm + (size_t)i * 512 + lane * 8);
    const float4* v4 = (const float4*)(b0 + lane * 8);
    float4 w0 = w4[0], w1 = w4[1], c0 = v4[0], c1 = v4[1];
    float acc = w0.x * c0.x + w0.y * c0.y + w0.z * c0.z + w0.w * c0.w +
                w1.x * c1.x + w1.y * c1.y + w1.z * c1.z + w1.w * c1.w;
#pragma unroll
    for (int off = 32; off; off >>= 1) acc += __shfl_xor(acc, off, 64);
    if (lane == 0) bc1[512 + z * 512 + i] = acc + bm[i];
  }
}

// ------------------------------- GEMM (B^T) --------------------------------
// C[m,n] = sum_k A[m,k] * Bt[n,k] + bias[n], bf16 planar store (ldc)
// 1D grid 1536, XCD-swizzled so each XCD owns contiguous M-panels
// (A-panel single-XCD L2 hit: FETCH 68.6 -> 20.5 MB, r3-verified).
// Two BK=32 slices staged per barrier pair (static LDS offsets, 8 drains).
__global__ __launch_bounds__(256) void gemm_bt(
    const __hip_bfloat16* __restrict__ A, int lda,
    const __hip_bfloat16* __restrict__ Bt,
    const float* __restrict__ bias,
    __hip_bfloat16* __restrict__ Cout, int ldc) {
  constexpr int K = 512, BK = 32;
  __shared__ __align__(16) __hip_bfloat16 As[2][128 * BK];   // 16 KB
  __shared__ __align__(16) __hip_bfloat16 Bs[2][128 * BK];   // 16 KB

  const int tid  = threadIdx.x;
  const int lane = tid & 63;
  const int w    = tid >> 6;
  const int wm   = w >> 1;
  const int wn   = w & 1;
  // bijective XCD swizzle: nwg=1536=8*192
  const int lb = (blockIdx.x & 7) * 192 + (blockIdx.x >> 3);
  const int by = lb / 12;
  const int bx = lb - by * 12;
  const int m0 = by * 128;
  const int n0 = bx * 128;

  const int rS0    = (w * 2 + 0) * 16 + (lane >> 2);
  const int rS1    = (w * 2 + 1) * 16 + (lane >> 2);
  const int kInRow = (lane & 3) * 8;
  const __hip_bfloat16* gA0 = A + (size_t)(m0 + rS0) * lda + kInRow;
  const __hip_bfloat16* gA1 = A + (size_t)(m0 + rS1) * lda + kInRow;
  const __hip_bfloat16* gB0 = Bt + (size_t)(n0 + rS0) * K + kInRow;
  const __hip_bfloat16* gB1 = Bt + (size_t)(n0 + rS1) * K + kInRow;
  char* ldsA0 = (char*)&As[0][0] + (w * 2 + 0) * 1024;
  char* ldsA1 = (char*)&As[0][0] + (w * 2 + 1) * 1024;
  char* ldsB0 = (char*)&Bs[0][0] + (w * 2 + 0) * 1024;
  char* ldsB1 = (char*)&Bs[0][0] + (w * 2 + 1) * 1024;

  f32x4 acc[4][4] = {};

  const int rfA = lane & 15;
  const int rfK = (lane >> 4) * 8;

  for (int kt = 0; kt < K; kt += 2 * BK) {
    __syncthreads();
    gll16(gA0 + kt, ldsA0);
    gll16(gA1 + kt, ldsA1);
    gll16(gB0 + kt, ldsB0);
    gll16(gB1 + kt, ldsB1);
    gll16(gA0 + kt + BK, ldsA0 + 8192);
    gll16(gA1 + kt + BK, ldsA1 + 8192);
    gll16(gB0 + kt + BK, ldsB0 + 8192);
    gll16(gB1 + kt + BK, ldsB1 + 8192);
    __syncthreads();

#pragma unroll
    for (int h = 0; h < 2; h++) {
      const __hip_bfloat16* Ah = &As[h][0];
      const __hip_bfloat16* Bh = &Bs[h][0];
      short8 af[4], bfv[4];
#pragma unroll
      for (int i = 0; i < 4; i++)
        af[i] = *(const short8*)(Ah + (wm * 64 + i * 16 + rfA) * BK + rfK);
#pragma unroll
      for (int j = 0; j < 4; j++)
        bfv[j] = *(const short8*)(Bh + (wn * 64 + j * 16 + rfA) * BK + rfK);
#pragma unroll
      for (int i = 0; i < 4; i++)
#pragma unroll
        for (int j = 0; j < 4; j++)
          acc[i][j] = __builtin_amdgcn_mfma_f32_16x16x32_bf16(
              af[i], bfv[j], acc[i][j], 0, 0, 0);
    }
  }

  const int cq = lane >> 4;
#pragma unroll
  for (int i = 0; i < 4; i++) {
    int row = m0 + wm * 64 + i * 16 + cq * 4;
#pragma unroll
    for (int j = 0; j < 4; j++) {
      int col = n0 + wn * 64 + j * 16 + (lane & 15);
      float bz = bias[col];
#pragma unroll
      for (int r = 0; r < 4; r++) {
        float v = acc[i][j][r] + bz;
        Cout[(size_t)(row + r) * ldc + col] = __float2bfloat16(v);
      }
    }
  }
}

// --------------- compose GEMM: Wkk=Wkm@Wk, Wqq=Wqm@Wq (MFMA) ---------------
__global__ __launch_bounds__(256) void gemm_compose(
    const __hip_bfloat16* __restrict__ Wm_bf,
    const __hip_bfloat16* __restrict__ WT_bf,
    __hip_bfloat16* __restrict__ Wall) {
  constexpr int K = 512, BK = 32;
  const __hip_bfloat16* A  = Wm_bf + (size_t)blockIdx.z * 262144;
  const __hip_bfloat16* Bt = WT_bf + (size_t)blockIdx.z * 262144;
  __hip_bfloat16* C = Wall + (size_t)(512 + blockIdx.z * 512) * 512;
  __shared__ __align__(16) __hip_bfloat16 As[128 * BK];
  __shared__ __align__(16) __hip_bfloat16 Bs[128 * BK];

  const int tid  = threadIdx.x;
  const int lane = tid & 63;
  const int w    = tid >> 6;
  const int wm   = w >> 1;
  const int wn   = w & 1;
  const int m0   = blockIdx.y * 128;
  const int n0   = blockIdx.x * 128;

  const int rS0    = (w * 2 + 0) * 16 + (lane >> 2);
  const int rS1    = (w * 2 + 1) * 16 + (lane >> 2);
  const int kInRow = (lane & 3) * 8;
  const __hip_bfloat16* gA0 = A + (size_t)(m0 + rS0) * K + kInRow;
  const __hip_bfloat16* gA1 = A + (size_t)(m0 + rS1) * K + kInRow;
  const __hip_bfloat16* gB0 = Bt + (size_t)(n0 + rS0) * K + kInRow;
  const __hip_bfloat16* gB1 = Bt + (size_t)(n0 + rS1) * K + kInRow;
  char* ldsA0 = (char*)As + (w * 2 + 0) * 1024;
  char* ldsA1 = (char*)As + (w * 2 + 1) * 1024;
  char* ldsB0 = (char*)Bs + (w * 2 + 0) * 1024;
  char* ldsB1 = (char*)Bs + (w * 2 + 1) * 1024;

  f32x4 acc[4][4] = {};
  const int rfA = lane & 15;
  const int rfK = (lane >> 4) * 8;

  for (int kt = 0; kt < K; kt += BK) {
    __syncthreads();
    gll16(gA0 + kt, ldsA0);
    gll16(gA1 + kt, ldsA1);
    gll16(gB0 + kt, ldsB0);
    gll16(gB1 + kt, ldsB1);
    __syncthreads();

    short8 af[4], bf[4];
#pragma unroll
    for (int i = 0; i < 4; i++)
      af[i] = *(const short8*)(As + (wm * 64 + i * 16 + rfA) * BK + rfK);
#pragma unroll
    for (int j = 0; j < 4; j++)
      bf[j] = *(const short8*)(Bs + (wn * 64 + j * 16 + rfA) * BK + rfK);
#pragma unroll
    for (int i = 0; i < 4; i++)
#pragma unroll
      for (int j = 0; j < 4; j++)
        acc[i][j] = __builtin_amdgcn_mfma_f32_16x16x32_bf16(
            af[i], bf[j], acc[i][j], 0, 0, 0);
  }

  const int cq = lane >> 4;
#pragma unroll
  for (int i = 0; i < 4; i++) {
    int row = m0 + wm * 64 + i * 16 + cq * 4;
#pragma unroll
    for (int j = 0; j < 4; j++) {
      int col = n0 + wn * 64 + j * 16 + (lane & 15);
#pragma unroll
      for (int r = 0; r < 4; r++)
        C[(size_t)(row + r) * 512 + col] = __float2bfloat16(acc[i][j][r]);
    }
  }
}

// ------ fused: phasor + split-scan cumsum + LN + GEMM(Wo) + resid ----------
// grid 256 (= B*nC), 1024 threads (16 waves). One chunk (64 tokens) / block.
// (round-6 proven version: 45.8 us, VGPR 44)
__global__ __launch_bounds__(1024) void fused_pg(
    const __hip_bfloat16* __restrict__ VKQ,   // [16384,1536] planar
    const float* __restrict__ bp,             // [4096,512]
    const float* __restrict__ mod_scale,
    const float* __restrict__ ln_g, const float* __restrict__ ln_b,
    const __hip_bfloat16* __restrict__ WoB,   // [512,512] bf16
    const float* __restrict__ bo,
    const float* __restrict__ x,              // resid f32
    float* __restrict__ out) {
  __shared__ __hip_bfloat16 R[64 * RPAD];     // 66.5 KB
  __shared__ float Tr[512], Ti[512];          // seg0 complex totals
  const int tid    = threadIdx.x;
  const int seg    = tid >> 9;                // 0 or 1
  const int d      = tid & 511;
  const int blk    = blockIdx.x;
  const int token0 = blk * 64;
  const int sg0    = (blk & (NCHUNK - 1)) * 64;
  const float msc  = mod_scale[0];
  const float isd  = 0.044194173824159216f;   // 1/sqrt(512)

  // ---- phase 1a: per-segment local phasor + cumsum (32 tokens) ----
  {
    const int s0 = seg * 32;
    float mr = 0.f, mi = 0.f;
    const __hip_bfloat16* vb = VKQ + (size_t)(token0 + s0) * 1536 + d;
    const float* bb = bp + (size_t)(sg0 + s0) * 512 + d;
#pragma unroll 4
    for (int s = 0; s < 32; ++s) {
      float v  = __bfloat162float(vb[(size_t)s * 1536]);
      float km = __bfloat162float(vb[(size_t)s * 1536 + 512]);
      float qm = __bfloat162float(vb[(size_t)s * 1536 + 1024]);
      float b  = bb[(size_t)s * 512];
      float kp = b + km * msc;
      float qp = b + qm * msc;
      float sk, ck, sq, cq;
      __sincosf(kp, &sk, &ck);
      __sincosf(qp, &sq, &cq);
      mr += v * ck;
      mi += v * sk;
      R[(s0 + s) * RPAD + d] = __float2bfloat16((mr * cq + mi * sq) * isd);
    }
    if (seg == 0) {
      Tr[d] = mr;
      Ti[d] = mi;
    }
  }
  __syncthreads();

  // ---- phase 1b: fixup rows 32..63 with seg0 prefix (all 1024 threads) ----
  {
    const int r0 = 32 + seg * 16;             // 16 rows per thread-half
    const float pr = Tr[d] * isd;
    const float pi = Ti[d] * isd;
    const __hip_bfloat16* qb = VKQ + (size_t)(token0 + r0) * 1536 + 1024 + d;
    const float* bb = bp + (size_t)(sg0 + r0) * 512 + d;
#pragma unroll 4
    for (int s = 0; s < 16; ++s) {
      float qm = __bfloat162float(qb[(size_t)s * 1536]);
      float b  = bb[(size_t)s * 512];
      float qp = b + qm * msc;
      float sq, cq;
      __sincosf(qp, &sq, &cq);
      int idx = (r0 + s) * RPAD + d;
      float v = __bfloat162float(R[idx]) + pr * cq + pi * sq;
      R[idx] = __float2bfloat16(v);
    }
  }
  __syncthreads();

  // ---- LayerNorm in place (wave wv owns rows wv*4..+3) ----
  {
    const int lane = tid & 63;
    const int wv   = tid >> 6;                // 0..15
    float gj[8], bj[8];
#pragma unroll
    for (int j = 0; j < 8; j++) {
      int col = lane + 64 * j;
      gj[j] = ln_g[col];
      bj[j] = ln_b[col];
    }
    for (int rr = 0; rr < 4; ++rr) {
      int row = wv * 4 + rr;
      float vals[8], sum = 0.f, sq2 = 0.f;
#pragma unroll
      for (int j = 0; j < 8; j++) {
        float v = __bfloat162float(R[row * RPAD + lane + 64 * j]);
        vals[j] = v;
        sum += v;
        sq2 += v * v;
      }
#pragma unroll
      for (int off = 32; off; off >>= 1) {
        sum += __shfl_xor(sum, off, 64);
        sq2 += __shfl_xor(sq2, off, 64);
      }
      float mu   = sum * (1.f / 512.f);
      float var  = sq2 * (1.f / 512.f) - mu * mu;
      float rstd = rsqrtf(var + 1e-5f);
#pragma unroll
      for (int j = 0; j < 8; j++) {
        float nv = (vals[j] - mu) * rstd * gj[j] + bj[j];
        R[row * RPAD + lane + 64 * j] = __float2bfloat16(nv);
      }
    }
  }
  __syncthreads();

  // ---- phase 2: C(64x512) = R @ WoB^T + bo + x -> out (16 waves) ----
  {
    const int lane = tid & 63;
    const int w    = tid >> 6;                // wave 0..15 -> cols w*32..+31
    const int rfA  = lane & 15;
    const int rfK  = (lane >> 4) * 8;
    f32x4 acc[4][2] = {};

    for (int kt = 0; kt < 512; kt += 32) {
      short8 af[4], bf[2];
#pragma unroll
      for (int j = 0; j < 2; j++) {
        int col = w * 32 + j * 16 + rfA;
        bf[j] = *(const short8*)(WoB + (size_t)col * 512 + kt + rfK);
      }
#pragma unroll
      for (int i = 0; i < 4; i++)
        af[i] = *(const short8*)(R + (i * 16 + rfA) * RPAD + kt + rfK);
#pragma unroll
      for (int i = 0; i < 4; i++)
#pragma unroll
        for (int j = 0; j < 2; j++)
          acc[i][j] = __builtin_amdgcn_mfma_f32_16x16x32_bf16(
              af[i], bf[j], acc[i][j], 0, 0, 0);
    }

    const int cq = lane >> 4;
    float bz[2];
#pragma unroll
    for (int j = 0; j < 2; j++) bz[j] = bo[w * 32 + j * 16 + (lane & 15)];
#pragma unroll
    for (int i = 0; i < 4; i++) {
      int row = token0 + i * 16 + cq * 4;
#pragma unroll
      for (int j = 0; j < 2; j++) {
        int col = w * 32 + j * 16 + (lane & 15);
#pragma unroll
        for (int r = 0; r < 4; r++) {
          size_t o = (size_t)(row + r) * 512 + col;
          out[o] = acc[i][j][r] + bz[j] + x[o];
        }
      }
    }
  }
}

// ------------------------------- launcher ----------------------------------
extern "C" void kernel_launch(void* const* d_in, const int* in_sizes, int n_in,
                              void* d_out, int out_size, void* d_ws,
                              size_t ws_size, hipStream_t stream) {
  const float* x    = (const float*)d_in[0];
  const float* bp   = (const float*)d_in[1];
  const float* Wk   = (const float*)d_in[2];
  const float* bk   = (const float*)d_in[3];
  const float* Wv   = (const float*)d_in[4];
  const float* bv   = (const float*)d_in[5];
  const float* Wq   = (const float*)d_in[6];
  const float* bq   = (const float*)d_in[7];
  const float* Wkm  = (const float*)d_in[8];
  const float* bkm  = (const float*)d_in[9];
  const float* Wqm  = (const float*)d_in[10];
  const float* bqm  = (const float*)d_in[11];
  const float* msc  = (const float*)d_in[12];
  const float* lng  = (const float*)d_in[13];
  const float* lnb  = (const float*)d_in[14];
  const float* Wo   = (const float*)d_in[15];
  const float* bo   = (const float*)d_in[16];
  float* out = (float*)d_out;

  char* ws = (char*)d_ws;
  __hip_bfloat16* x_bf  = (__hip_bfloat16*)ws;  ws += (size_t)M_TOK * DIM * 2;
  __hip_bfloat16* Wall  = (__hip_bfloat16*)ws;  ws += (size_t)2048 * 512 * 2;
  __hip_bfloat16* Wm_bf = (__hip_bfloat16*)ws;  ws += (size_t)2 * 262144 * 2;
  __hip_bfloat16* WT_bf = (__hip_bfloat16*)ws;  ws += (size_t)2 * 262144 * 2;
  float*          bc1   = (float*)ws;           ws += 1536 * 4;
  __hip_bfloat16* VKQ   = (__hip_bfloat16*)ws;  ws += (size_t)M_TOK * 1536 * 2;

  // 1) merged prep: cvt x + pack/cvt/transpose weights + compose biases
  prep_all<<<9600, 256, 0, stream>>>(x, x_bf, Wv, Wo, bv, Wkm, Wqm, Wk, Wq,
                                     bk, bkm, bq, bqm, Wall, bc1, Wm_bf,
                                     WT_bf);
  // 2) MFMA compose: Wkk, Wqq -> Wall rows 512..1535
  gemm_compose<<<dim3(4, 4, 2), 256, 0, stream>>>(Wm_bf, WT_bf, Wall);
  // 3) VKQ = x @ [Wv|Wkk|Wqq]^T + bias, planar [16384,1536]
  gemm_bt<<<dim3(1536), 256, 0, stream>>>(x_bf, DIM, Wall, bc1, VKQ, 1536);
  // 4) fused phasor + split-scan cumsum + LN + GEMM(Wo) + bo + resid -> out
  fused_pg<<<256, 1024, 0, stream>>>(VKQ, bp, msc, lng, lnb,
                                     Wall + (size_t)1536 * 512, bo, x, out);
}

// Round 5
// 201.929 us; speedup vs baseline: 1.2459x; 1.0052x over previous
//
#include <hip/hip_runtime.h>
#include <hip/hip_bf16.h>

// ---------------------------------------------------------------------------
// OrthoInitPhasor round 11
//   prep_all:     cvt x->bf16, pack Wv/Wo, cvt Wkm/Wqm, transpose Wk/Wq,
//                 compose biases
//   gemm_compose: Wkk = Wkm@Wk, Wqq = Wqm@Wq via MFMA
//   gemm_bt:      x @ [Wv|Wkk|Wqq]^T + bias -> VKQ planar [16384,1536] bf16
//                 XCD-swizzled grid + COUNTED-VMCNT 2-deep pipeline:
//                 raw s_barrier + s_waitcnt vmcnt(4) (never 0 in main loop),
//                 next-tile loads stay in flight across barriers (T3+T4),
//                 static buffer offsets (macro-literal), setprio MFMA (T5)
//   fused_pg:     r6-proven monolith (45.8 us, VGPR 44): 1024-thr 2-segment
//                 split-scan phasor+cumsum+LN + MFMA GEMM(Wo) + resid
// ---------------------------------------------------------------------------

typedef __attribute__((ext_vector_type(8))) short short8;   // 8 x bf16
typedef __attribute__((ext_vector_type(4))) float f32x4;

#define M_TOK   16384
#define DIM     512
#define NCHUNK  64
#define RPAD    520   // LDS row stride (bf16 elems) for normed tile

__device__ __forceinline__ void gll16(const void* g, void* l) {
  __builtin_amdgcn_global_load_lds(
      (const __attribute__((address_space(1))) unsigned int*)g,
      (__attribute__((address_space(3))) unsigned int*)l, 16, 0, 0);
}

__device__ __forceinline__ uint2 pack4bf(float4 v) {
  union { __hip_bfloat16 h[4]; uint2 u; } t;
  t.h[0] = __float2bfloat16(v.x);
  t.h[1] = __float2bfloat16(v.y);
  t.h[2] = __float2bfloat16(v.z);
  t.h[3] = __float2bfloat16(v.w);
  return t.u;
}

// ------------------------------ prep (merged) ------------------------------
__global__ __launch_bounds__(256) void prep_all(
    const float* __restrict__ x, __hip_bfloat16* __restrict__ x_bf,
    const float* __restrict__ Wv, const float* __restrict__ Wo,
    const float* __restrict__ bv,
    const float* __restrict__ Wkm, const float* __restrict__ Wqm,
    const float* __restrict__ Wk, const float* __restrict__ Wq,
    const float* __restrict__ bk, const float* __restrict__ bkm,
    const float* __restrict__ bq, const float* __restrict__ bqm,
    __hip_bfloat16* __restrict__ Wall, float* __restrict__ bc1,
    __hip_bfloat16* __restrict__ Wm_bf, __hip_bfloat16* __restrict__ WT_bf) {
  const int tid = threadIdx.x;
  if (blockIdx.x < 8192) {
    int i = blockIdx.x * 256 + tid;          // 2097152 float4s
    ((uint2*)x_bf)[i] = pack4bf(((const float4*)x)[i]);
    return;
  }
  const int b = blockIdx.x - 8192;
  if (b < 512) {
    int m = b >> 8;
    int idx = ((b & 255) * 256 + tid) * 4;
    const float* src = m ? Wo : Wv;
    __hip_bfloat16* dst = Wall + (m ? (size_t)1536 * 512 : 0);
    ((uint2*)dst)[idx >> 2] = pack4bf(*(const float4*)(src + idx));
    int t = b * 256 + tid;
    if (t < 512) bc1[t] = bv[t];
  } else if (b < 1024) {
    int bb = b - 512;
    int m = bb >> 8;
    int idx = ((bb & 255) * 256 + tid) * 4;
    const float* src = m ? Wqm : Wkm;
    ((uint2*)(Wm_bf + (size_t)m * 262144))[idx >> 2] =
        pack4bf(*(const float4*)(src + idx));
  } else if (b < 1152) {
    __shared__ float tile[64][65];
    int bb = b - 1024;
    int z = bb >> 6;
    int tl = bb & 63;
    int tr = tl >> 3, tc = tl & 7;
    const float* src = z ? Wq : Wk;
#pragma unroll
    for (int i = 0; i < 4; i++) {
      int r = (tid >> 4) + 16 * i;
      int c4 = (tid & 15) * 4;
      float4 v = *(const float4*)(src + (size_t)(tr * 64 + r) * 512 +
                                  tc * 64 + c4);
      tile[r][c4 + 0] = v.x;
      tile[r][c4 + 1] = v.y;
      tile[r][c4 + 2] = v.z;
      tile[r][c4 + 3] = v.w;
    }
    __syncthreads();
    int orow = tid >> 2;
    int seg = tid & 3;
    __hip_bfloat16* dst = WT_bf + (size_t)z * 262144 +
                          (size_t)(tc * 64 + orow) * 512 + tr * 64 + seg * 16;
#pragma unroll
    for (int q = 0; q < 4; q++) {
      float4 v;
      v.x = tile[seg * 16 + q * 4 + 0][orow];
      v.y = tile[seg * 16 + q * 4 + 1][orow];
      v.z = tile[seg * 16 + q * 4 + 2][orow];
      v.w = tile[seg * 16 + q * 4 + 3][orow];
      *(uint2*)(dst + q * 4) = pack4bf(v);
    }
  } else {
    int row = (b - 1152) * 4 + (tid >> 6);
    int lane = tid & 63;
    int z = row >> 9;
    int i = row & 511;
    const float* Wm = z ? Wqm : Wkm;
    const float* b0 = z ? bq : bk;
    const float* bm = z ? bqm : bkm;
    const float4* w4 = (const float4*)(Wm + (size_t)i * 512 + lane * 8);
    const float4* v4 = (const float4*)(b0 + lane * 8);
    float4 w0 = w4[0], w1 = w4[1], c0 = v4[0], c1 = v4[1];
    float acc = w0.x * c0.x + w0.y * c0.y + w0.z * c0.z + w0.w * c0.w +
                w1.x * c1.x + w1.y * c1.y + w1.z * c1.z + w1.w * c1.w;
#pragma unroll
    for (int off = 32; off; off >>= 1) acc += __shfl_xor(acc, off, 64);
    if (lane == 0) bc1[512 + z * 512 + i] = acc + bm[i];
  }
}

// ------------------------------- GEMM (B^T) --------------------------------
// C[m,n] = sum_k A[m,k] * Bt[n,k] + bias[n], bf16 planar store (ldc)
// 1D grid 1536, XCD-swizzled (FETCH 68.6 -> 20.5 MB, r3-verified).
// Counted-vmcnt 2-deep pipeline: per tile
//   {vmcnt(4); s_barrier; ds_read cur; lgkmcnt(0); s_barrier;
//    stage(t+2 -> cur); setprio(1); 16xMFMA; setprio(0)}
// vmcnt never drains to 0 in the main loop (T4); loads span 2 tiles.
#define GTILE(BUF, T, STAGE_EN, WN)                                         \
  {                                                                         \
    asm volatile("s_waitcnt vmcnt(" WN ")" ::: "memory");                   \
    __builtin_amdgcn_s_barrier();                                           \
    short8 af[4], bfv[4];                                                   \
    _Pragma("unroll") for (int i = 0; i < 4; i++)                           \
      af[i] = *(const short8*)(&As[BUF][0] +                                \
                               (wm * 64 + i * 16 + rfA) * BK + rfK);        \
    _Pragma("unroll") for (int j = 0; j < 4; j++)                           \
      bfv[j] = *(const short8*)(&Bs[BUF][0] +                               \
                                (wn * 64 + j * 16 + rfA) * BK + rfK);       \
    if (STAGE_EN) {                                                         \
      asm volatile("s_waitcnt lgkmcnt(0)" ::: "memory");                    \
      __builtin_amdgcn_s_barrier();                                         \
      const int nk = ((T) + 2) * BK;                                        \
      gll16(gA0 + nk, ldsA0 + (BUF) * 8192);                                \
      gll16(gA1 + nk, ldsA1 + (BUF) * 8192);                                \
      gll16(gB0 + nk, ldsB0 + (BUF) * 8192);                                \
      gll16(gB1 + nk, ldsB1 + (BUF) * 8192);                                \
    }                                                                       \
    __builtin_amdgcn_s_setprio(1);                                          \
    _Pragma("unroll") for (int i = 0; i < 4; i++)                           \
      _Pragma("unroll") for (int j = 0; j < 4; j++)                         \
        acc[i][j] = __builtin_amdgcn_mfma_f32_16x16x32_bf16(                \
            af[i], bfv[j], acc[i][j], 0, 0, 0);                             \
    __builtin_amdgcn_s_setprio(0);                                          \
  }

__global__ __launch_bounds__(256) void gemm_bt(
    const __hip_bfloat16* __restrict__ A, int lda,
    const __hip_bfloat16* __restrict__ Bt,
    const float* __restrict__ bias,
    __hip_bfloat16* __restrict__ Cout, int ldc) {
  constexpr int K = 512, BK = 32;
  __shared__ __align__(16) __hip_bfloat16 As[2][128 * BK];   // 16 KB
  __shared__ __align__(16) __hip_bfloat16 Bs[2][128 * BK];   // 16 KB

  const int tid  = threadIdx.x;
  const int lane = tid & 63;
  const int w    = tid >> 6;
  const int wm   = w >> 1;
  const int wn   = w & 1;
  // bijective XCD swizzle: nwg=1536=8*192
  const int lb = (blockIdx.x & 7) * 192 + (blockIdx.x >> 3);
  const int by = lb / 12;
  const int bx = lb - by * 12;
  const int m0 = by * 128;
  const int n0 = bx * 128;

  const int rS0    = (w * 2 + 0) * 16 + (lane >> 2);
  const int rS1    = (w * 2 + 1) * 16 + (lane >> 2);
  const int kInRow = (lane & 3) * 8;
  const __hip_bfloat16* gA0 = A + (size_t)(m0 + rS0) * lda + kInRow;
  const __hip_bfloat16* gA1 = A + (size_t)(m0 + rS1) * lda + kInRow;
  const __hip_bfloat16* gB0 = Bt + (size_t)(n0 + rS0) * K + kInRow;
  const __hip_bfloat16* gB1 = Bt + (size_t)(n0 + rS1) * K + kInRow;
  char* ldsA0 = (char*)&As[0][0] + (w * 2 + 0) * 1024;
  char* ldsA1 = (char*)&As[0][0] + (w * 2 + 1) * 1024;
  char* ldsB0 = (char*)&Bs[0][0] + (w * 2 + 0) * 1024;
  char* ldsB1 = (char*)&Bs[0][0] + (w * 2 + 1) * 1024;

  f32x4 acc[4][4] = {};

  const int rfA = lane & 15;
  const int rfK = (lane >> 4) * 8;

  // prologue: stage tiles 0 (buf0) and 1 (buf1): 8 loads in flight/thread
  gll16(gA0, ldsA0);
  gll16(gA1, ldsA1);
  gll16(gB0, ldsB0);
  gll16(gB1, ldsB1);
  gll16(gA0 + BK, ldsA0 + 8192);
  gll16(gA1 + BK, ldsA1 + 8192);
  gll16(gB0 + BK, ldsB0 + 8192);
  gll16(gB1 + BK, ldsB1 + 8192);

#pragma unroll
  for (int t = 0; t < 14; t += 2) {
    GTILE(0, t, 1, "4");
    GTILE(1, t + 1, 1, "4");
  }
  GTILE(0, 14, 0, "4");
  GTILE(1, 15, 0, "0");

  const int cq = lane >> 4;
#pragma unroll
  for (int i = 0; i < 4; i++) {
    int row = m0 + wm * 64 + i * 16 + cq * 4;
#pragma unroll
    for (int j = 0; j < 4; j++) {
      int col = n0 + wn * 64 + j * 16 + (lane & 15);
      float bz = bias[col];
#pragma unroll
      for (int r = 0; r < 4; r++) {
        float v = acc[i][j][r] + bz;
        Cout[(size_t)(row + r) * ldc + col] = __float2bfloat16(v);
      }
    }
  }
}

// --------------- compose GEMM: Wkk=Wkm@Wk, Wqq=Wqm@Wq (MFMA) ---------------
__global__ __launch_bounds__(256) void gemm_compose(
    const __hip_bfloat16* __restrict__ Wm_bf,
    const __hip_bfloat16* __restrict__ WT_bf,
    __hip_bfloat16* __restrict__ Wall) {
  constexpr int K = 512, BK = 32;
  const __hip_bfloat16* A  = Wm_bf + (size_t)blockIdx.z * 262144;
  const __hip_bfloat16* Bt = WT_bf + (size_t)blockIdx.z * 262144;
  __hip_bfloat16* C = Wall + (size_t)(512 + blockIdx.z * 512) * 512;
  __shared__ __align__(16) __hip_bfloat16 As[128 * BK];
  __shared__ __align__(16) __hip_bfloat16 Bs[128 * BK];

  const int tid  = threadIdx.x;
  const int lane = tid & 63;
  const int w    = tid >> 6;
  const int wm   = w >> 1;
  const int wn   = w & 1;
  const int m0   = blockIdx.y * 128;
  const int n0   = blockIdx.x * 128;

  const int rS0    = (w * 2 + 0) * 16 + (lane >> 2);
  const int rS1    = (w * 2 + 1) * 16 + (lane >> 2);
  const int kInRow = (lane & 3) * 8;
  const __hip_bfloat16* gA0 = A + (size_t)(m0 + rS0) * K + kInRow;
  const __hip_bfloat16* gA1 = A + (size_t)(m0 + rS1) * K + kInRow;
  const __hip_bfloat16* gB0 = Bt + (size_t)(n0 + rS0) * K + kInRow;
  const __hip_bfloat16* gB1 = Bt + (size_t)(n0 + rS1) * K + kInRow;
  char* ldsA0 = (char*)As + (w * 2 + 0) * 1024;
  char* ldsA1 = (char*)As + (w * 2 + 1) * 1024;
  char* ldsB0 = (char*)Bs + (w * 2 + 0) * 1024;
  char* ldsB1 = (char*)Bs + (w * 2 + 1) * 1024;

  f32x4 acc[4][4] = {};
  const int rfA = lane & 15;
  const int rfK = (lane >> 4) * 8;

  for (int kt = 0; kt < K; kt += BK) {
    __syncthreads();
    gll16(gA0 + kt, ldsA0);
    gll16(gA1 + kt, ldsA1);
    gll16(gB0 + kt, ldsB0);
    gll16(gB1 + kt, ldsB1);
    __syncthreads();

    short8 af[4], bf[4];
#pragma unroll
    for (int i = 0; i < 4; i++)
      af[i] = *(const short8*)(As + (wm * 64 + i * 16 + rfA) * BK + rfK);
#pragma unroll
    for (int j = 0; j < 4; j++)
      bf[j] = *(const short8*)(Bs + (wn * 64 + j * 16 + rfA) * BK + rfK);
#pragma unroll
    for (int i = 0; i < 4; i++)
#pragma unroll
      for (int j = 0; j < 4; j++)
        acc[i][j] = __builtin_amdgcn_mfma_f32_16x16x32_bf16(
            af[i], bf[j], acc[i][j], 0, 0, 0);
  }

  const int cq = lane >> 4;
#pragma unroll
  for (int i = 0; i < 4; i++) {
    int row = m0 + wm * 64 + i * 16 + cq * 4;
#pragma unroll
    for (int j = 0; j < 4; j++) {
      int col = n0 + wn * 64 + j * 16 + (lane & 15);
#pragma unroll
      for (int r = 0; r < 4; r++)
        C[(size_t)(row + r) * 512 + col] = __float2bfloat16(acc[i][j][r]);
    }
  }
}

// ------ fused: phasor + split-scan cumsum + LN + GEMM(Wo) + resid ----------
// grid 256 (= B*nC), 1024 threads (16 waves). One chunk (64 tokens) / block.
// (round-6 proven version: 45.8 us, VGPR 44)
__global__ __launch_bounds__(1024) void fused_pg(
    const __hip_bfloat16* __restrict__ VKQ,   // [16384,1536] planar
    const float* __restrict__ bp,             // [4096,512]
    const float* __restrict__ mod_scale,
    const float* __restrict__ ln_g, const float* __restrict__ ln_b,
    const __hip_bfloat16* __restrict__ WoB,   // [512,512] bf16
    const float* __restrict__ bo,
    const float* __restrict__ x,              // resid f32
    float* __restrict__ out) {
  __shared__ __hip_bfloat16 R[64 * RPAD];     // 66.5 KB
  __shared__ float Tr[512], Ti[512];          // seg0 complex totals
  const int tid    = threadIdx.x;
  const int seg    = tid >> 9;                // 0 or 1
  const int d      = tid & 511;
  const int blk    = blockIdx.x;
  const int token0 = blk * 64;
  const int sg0    = (blk & (NCHUNK - 1)) * 64;
  const float msc  = mod_scale[0];
  const float isd  = 0.044194173824159216f;   // 1/sqrt(512)

  // ---- phase 1a: per-segment local phasor + cumsum (32 tokens) ----
  {
    const int s0 = seg * 32;
    float mr = 0.f, mi = 0.f;
    const __hip_bfloat16* vb = VKQ + (size_t)(token0 + s0) * 1536 + d;
    const float* bb = bp + (size_t)(sg0 + s0) * 512 + d;
#pragma unroll 4
    for (int s = 0; s < 32; ++s) {
      float v  = __bfloat162float(vb[(size_t)s * 1536]);
      float km = __bfloat162float(vb[(size_t)s * 1536 + 512]);
      float qm = __bfloat162float(vb[(size_t)s * 1536 + 1024]);
      float b  = bb[(size_t)s * 512];
      float kp = b + km * msc;
      float qp = b + qm * msc;
      float sk, ck, sq, cq;
      __sincosf(kp, &sk, &ck);
      __sincosf(qp, &sq, &cq);
      mr += v * ck;
      mi += v * sk;
      R[(s0 + s) * RPAD + d] = __float2bfloat16((mr * cq + mi * sq) * isd);
    }
    if (seg == 0) {
      Tr[d] = mr;
      Ti[d] = mi;
    }
  }
  __syncthreads();

  // ---- phase 1b: fixup rows 32..63 with seg0 prefix (all 1024 threads) ----
  {
    const int r0 = 32 + seg * 16;             // 16 rows per thread-half
    const float pr = Tr[d] * isd;
    const float pi = Ti[d] * isd;
    const __hip_bfloat16* qb = VKQ + (size_t)(token0 + r0) * 1536 + 1024 + d;
    const float* bb = bp + (size_t)(sg0 + r0) * 512 + d;
#pragma unroll 4
    for (int s = 0; s < 16; ++s) {
      float qm = __bfloat162float(qb[(size_t)s * 1536]);
      float b  = bb[(size_t)s * 512];
      float qp = b + qm * msc;
      float sq, cq;
      __sincosf(qp, &sq, &cq);
      int idx = (r0 + s) * RPAD + d;
      float v = __bfloat162float(R[idx]) + pr * cq + pi * sq;
      R[idx] = __float2bfloat16(v);
    }
  }
  __syncthreads();

  // ---- LayerNorm in place (wave wv owns rows wv*4..+3) ----
  {
    const int lane = tid & 63;
    const int wv   = tid >> 6;                // 0..15
    float gj[8], bj[8];
#pragma unroll
    for (int j = 0; j < 8; j++) {
      int col = lane + 64 * j;
      gj[j] = ln_g[col];
      bj[j] = ln_b[col];
    }
    for (int rr = 0; rr < 4; ++rr) {
      int row = wv * 4 + rr;
      float vals[8], sum = 0.f, sq2 = 0.f;
#pragma unroll
      for (int j = 0; j < 8; j++) {
        float v = __bfloat162float(R[row * RPAD + lane + 64 * j]);
        vals[j] = v;
        sum += v;
        sq2 += v * v;
      }
#pragma unroll
      for (int off = 32; off; off >>= 1) {
        sum += __shfl_xor(sum, off, 64);
        sq2 += __shfl_xor(sq2, off, 64);
      }
      float mu   = sum * (1.f / 512.f);
      float var  = sq2 * (1.f / 512.f) - mu * mu;
      float rstd = rsqrtf(var + 1e-5f);
#pragma unroll
      for (int j = 0; j < 8; j++) {
        float nv = (vals[j] - mu) * rstd * gj[j] + bj[j];
        R[row * RPAD + lane + 64 * j] = __float2bfloat16(nv);
      }
    }
  }
  __syncthreads();

  // ---- phase 2: C(64x512) = R @ WoB^T + bo + x -> out (16 waves) ----
  {
    const int lane = tid & 63;
    const int w    = tid >> 6;                // wave 0..15 -> cols w*32..+31
    const int rfA  = lane & 15;
    const int rfK  = (lane >> 4) * 8;
    f32x4 acc[4][2] = {};

    for (int kt = 0; kt < 512; kt += 32) {
      short8 af[4], bf[2];
#pragma unroll
      for (int j = 0; j < 2; j++) {
        int col = w * 32 + j * 16 + rfA;
        bf[j] = *(const short8*)(WoB + (size_t)col * 512 + kt + rfK);
      }
#pragma unroll
      for (int i = 0; i < 4; i++)
        af[i] = *(const short8*)(R + (i * 16 + rfA) * RPAD + kt + rfK);
#pragma unroll
      for (int i = 0; i < 4; i++)
#pragma unroll
        for (int j = 0; j < 2; j++)
          acc[i][j] = __builtin_amdgcn_mfma_f32_16x16x32_bf16(
              af[i], bf[j], acc[i][j], 0, 0, 0);
    }

    const int cq = lane >> 4;
    float bz[2];
#pragma unroll
    for (int j = 0; j < 2; j++) bz[j] = bo[w * 32 + j * 16 + (lane & 15)];
#pragma unroll
    for (int i = 0; i < 4; i++) {
      int row = token0 + i * 16 + cq * 4;
#pragma unroll
      for (int j = 0; j < 2; j++) {
        int col = w * 32 + j * 16 + (lane & 15);
#pragma unroll
        for (int r = 0; r < 4; r++) {
          size_t o = (size_t)(row + r) * 512 + col;
          out[o] = acc[i][j][r] + bz[j] + x[o];
        }
      }
    }
  }
}

// ------------------------------- launcher ----------------------------------
extern "C" void kernel_launch(void* const* d_in, const int* in_sizes, int n_in,
                              void* d_out, int out_size, void* d_ws,
                              size_t ws_size, hipStream_t stream) {
  const float* x    = (const float*)d_in[0];
  const float* bp   = (const float*)d_in[1];
  const float* Wk   = (const float*)d_in[2];
  const float* bk   = (const float*)d_in[3];
  const float* Wv   = (const float*)d_in[4];
  const float* bv   = (const float*)d_in[5];
  const float* Wq   = (const float*)d_in[6];
  const float* bq   = (const float*)d_in[7];
  const float* Wkm  = (const float*)d_in[8];
  const float* bkm  = (const float*)d_in[9];
  const float* Wqm  = (const float*)d_in[10];
  const float* bqm  = (const float*)d_in[11];
  const float* msc  = (const float*)d_in[12];
  const float* lng  = (const float*)d_in[13];
  const float* lnb  = (const float*)d_in[14];
  const float* Wo   = (const float*)d_in[15];
  const float* bo   = (const float*)d_in[16];
  float* out = (float*)d_out;

  char* ws = (char*)d_ws;
  __hip_bfloat16* x_bf  = (__hip_bfloat16*)ws;  ws += (size_t)M_TOK * DIM * 2;
  __hip_bfloat16* Wall  = (__hip_bfloat16*)ws;  ws += (size_t)2048 * 512 * 2;
  __hip_bfloat16* Wm_bf = (__hip_bfloat16*)ws;  ws += (size_t)2 * 262144 * 2;
  __hip_bfloat16* WT_bf = (__hip_bfloat16*)ws;  ws += (size_t)2 * 262144 * 2;
  float*          bc1   = (float*)ws;           ws += 1536 * 4;
  __hip_bfloat16* VKQ   = (__hip_bfloat16*)ws;  ws += (size_t)M_TOK * 1536 * 2;

  // 1) merged prep: cvt x + pack/cvt/transpose weights + compose biases
  prep_all<<<9600, 256, 0, stream>>>(x, x_bf, Wv, Wo, bv, Wkm, Wqm, Wk, Wq,
                                     bk, bkm, bq, bqm, Wall, bc1, Wm_bf,
                                     WT_bf);
  // 2) MFMA compose: Wkk, Wqq -> Wall rows 512..1535
  gemm_compose<<<dim3(4, 4, 2), 256, 0, stream>>>(Wm_bf, WT_bf, Wall);
  // 3) VKQ = x @ [Wv|Wkk|Wqq]^T + bias, planar [16384,1536]
  gemm_bt<<<dim3(1536), 256, 0, stream>>>(x_bf, DIM, Wall, bc1, VKQ, 1536);
  // 4) fused phasor + split-scan cumsum + LN + GEMM(Wo) + bo + resid -> out
  fused_pg<<<256, 1024, 0, stream>>>(VKQ, bp, msc, lng, lnb,
                                     Wall + (size_t)1536 * 512, bo, x, out);
}

// Round 6
// 201.531 us; speedup vs baseline: 1.2483x; 1.0020x over previous
//
#include <hip/hip_runtime.h>
#include <hip/hip_bf16.h>

// ---------------------------------------------------------------------------
// OrthoInitPhasor round 12
//   prep_all:     cvt x->bf16, pack Wv/Wo, cvt Wkm/Wqm, transpose Wk/Wq,
//                 compose biases
//   gemm_compose: Wkk = Wkm@Wk, Wqq = Wqm@Wq via MFMA
//   gemm_bt:      x @ [Wv|Wkk|Wqq]^T + bias -> VKQ planar [16384,1536] bf16
//                 RETILED: 768 blocks of 128x256, 512 thr / 8 waves (2Mx4N),
//                 per-wave 64x64 (r1-identical registers ~92 VGPR),
//                 2-slice staging per barrier pair, XCD swizzle (8x96).
//                 Halves A-panel refetch + halves prologue/drain events.
//   fused_pg:     r6-proven monolith (45.8 us, VGPR 44): 1024-thr 2-segment
//                 split-scan phasor+cumsum+LN + MFMA GEMM(Wo) + resid
// ---------------------------------------------------------------------------

typedef __attribute__((ext_vector_type(8))) short short8;   // 8 x bf16
typedef __attribute__((ext_vector_type(4))) float f32x4;

#define M_TOK   16384
#define DIM     512
#define NCHUNK  64
#define RPAD    520   // LDS row stride (bf16 elems) for normed tile

__device__ __forceinline__ void gll16(const void* g, void* l) {
  __builtin_amdgcn_global_load_lds(
      (const __attribute__((address_space(1))) unsigned int*)g,
      (__attribute__((address_space(3))) unsigned int*)l, 16, 0, 0);
}

__device__ __forceinline__ uint2 pack4bf(float4 v) {
  union { __hip_bfloat16 h[4]; uint2 u; } t;
  t.h[0] = __float2bfloat16(v.x);
  t.h[1] = __float2bfloat16(v.y);
  t.h[2] = __float2bfloat16(v.z);
  t.h[3] = __float2bfloat16(v.w);
  return t.u;
}

// ------------------------------ prep (merged) ------------------------------
__global__ __launch_bounds__(256) void prep_all(
    const float* __restrict__ x, __hip_bfloat16* __restrict__ x_bf,
    const float* __restrict__ Wv, const float* __restrict__ Wo,
    const float* __restrict__ bv,
    const float* __restrict__ Wkm, const float* __restrict__ Wqm,
    const float* __restrict__ Wk, const float* __restrict__ Wq,
    const float* __restrict__ bk, const float* __restrict__ bkm,
    const float* __restrict__ bq, const float* __restrict__ bqm,
    __hip_bfloat16* __restrict__ Wall, float* __restrict__ bc1,
    __hip_bfloat16* __restrict__ Wm_bf, __hip_bfloat16* __restrict__ WT_bf) {
  const int tid = threadIdx.x;
  if (blockIdx.x < 8192) {
    int i = blockIdx.x * 256 + tid;          // 2097152 float4s
    ((uint2*)x_bf)[i] = pack4bf(((const float4*)x)[i]);
    return;
  }
  const int b = blockIdx.x - 8192;
  if (b < 512) {
    int m = b >> 8;
    int idx = ((b & 255) * 256 + tid) * 4;
    const float* src = m ? Wo : Wv;
    __hip_bfloat16* dst = Wall + (m ? (size_t)1536 * 512 : 0);
    ((uint2*)dst)[idx >> 2] = pack4bf(*(const float4*)(src + idx));
    int t = b * 256 + tid;
    if (t < 512) bc1[t] = bv[t];
  } else if (b < 1024) {
    int bb = b - 512;
    int m = bb >> 8;
    int idx = ((bb & 255) * 256 + tid) * 4;
    const float* src = m ? Wqm : Wkm;
    ((uint2*)(Wm_bf + (size_t)m * 262144))[idx >> 2] =
        pack4bf(*(const float4*)(src + idx));
  } else if (b < 1152) {
    __shared__ float tile[64][65];
    int bb = b - 1024;
    int z = bb >> 6;
    int tl = bb & 63;
    int tr = tl >> 3, tc = tl & 7;
    const float* src = z ? Wq : Wk;
#pragma unroll
    for (int i = 0; i < 4; i++) {
      int r = (tid >> 4) + 16 * i;
      int c4 = (tid & 15) * 4;
      float4 v = *(const float4*)(src + (size_t)(tr * 64 + r) * 512 +
                                  tc * 64 + c4);
      tile[r][c4 + 0] = v.x;
      tile[r][c4 + 1] = v.y;
      tile[r][c4 + 2] = v.z;
      tile[r][c4 + 3] = v.w;
    }
    __syncthreads();
    int orow = tid >> 2;
    int seg = tid & 3;
    __hip_bfloat16* dst = WT_bf + (size_t)z * 262144 +
                          (size_t)(tc * 64 + orow) * 512 + tr * 64 + seg * 16;
#pragma unroll
    for (int q = 0; q < 4; q++) {
      float4 v;
      v.x = tile[seg * 16 + q * 4 + 0][orow];
      v.y = tile[seg * 16 + q * 4 + 1][orow];
      v.z = tile[seg * 16 + q * 4 + 2][orow];
      v.w = tile[seg * 16 + q * 4 + 3][orow];
      *(uint2*)(dst + q * 4) = pack4bf(v);
    }
  } else {
    int row = (b - 1152) * 4 + (tid >> 6);
    int lane = tid & 63;
    int z = row >> 9;
    int i = row & 511;
    const float* Wm = z ? Wqm : Wkm;
    const float* b0 = z ? bq : bk;
    const float* bm = z ? bqm : bkm;
    const float4* w4 = (const float4*)(Wm + (size_t)i * 512 + lane * 8);
    const float4* v4 = (const float4*)(b0 + lane * 8);
    float4 w0 = w4[0], w1 = w4[1], c0 = v4[0], c1 = v4[1];
    float acc = w0.x * c0.x + w0.y * c0.y + w0.z * c0.z + w0.w * c0.w +
                w1.x * c1.x + w1.y * c1.y + w1.z * c1.z + w1.w * c1.w;
#pragma unroll
    for (int off = 32; off; off >>= 1) acc += __shfl_xor(acc, off, 64);
    if (lane == 0) bc1[512 + z * 512 + i] = acc + bm[i];
  }
}

// ------------------------------- GEMM (B^T) --------------------------------
// C[m,n] = sum_k A[m,k] * Bt[n,k] + bias[n], bf16 planar store (ldc)
// 768 blocks (128x256 tile), 512 threads = 8 waves (2M x 4N), per-wave 64x64.
// XCD swizzle: nwg=768=8*96 bijective; each XCD owns 16 contiguous M-panels.
// Two BK=32 slices staged per barrier pair (1xA + 2xB gll16 per thread each).
__global__ __launch_bounds__(512) void gemm_bt(
    const __hip_bfloat16* __restrict__ A, int lda,
    const __hip_bfloat16* __restrict__ Bt,
    const float* __restrict__ bias,
    __hip_bfloat16* __restrict__ Cout, int ldc) {
  constexpr int K = 512, BK = 32;
  __shared__ __align__(16) __hip_bfloat16 As[2][128 * BK];   // 2 x 8 KB
  __shared__ __align__(16) __hip_bfloat16 Bs[2][256 * BK];   // 2 x 16 KB

  const int tid  = threadIdx.x;
  const int lane = tid & 63;
  const int w    = tid >> 6;     // 0..7
  const int wm   = w >> 2;       // 0..1 -> rows wm*64..+63
  const int wn   = w & 3;        // 0..3 -> cols wn*64..+63
  // bijective XCD swizzle: nwg=768=8*96
  const int lb = (blockIdx.x & 7) * 96 + (blockIdx.x >> 3);
  const int by = lb / 6;
  const int bx = lb - by * 6;
  const int m0 = by * 128;
  const int n0 = bx * 256;

  // staging: thread t covers 16B at row t>>2, k-offset (t&3)*8
  const int rS  = tid >> 2;                 // 0..127
  const int kIn = (tid & 3) * 8;
  const __hip_bfloat16* gA  = A  + (size_t)(m0 + rS) * lda + kIn;
  const __hip_bfloat16* gB0 = Bt + (size_t)(n0 + rS) * K + kIn;        // rows 0..127
  const __hip_bfloat16* gB1 = Bt + (size_t)(n0 + 128 + rS) * K + kIn;  // rows 128..255
  // gll16 LDS dest = wave-uniform base (+ HW lane*16)
  char* ldsA  = (char*)&As[0][0] + w * 1024;
  char* ldsB0 = (char*)&Bs[0][0] + w * 1024;
  char* ldsB1 = (char*)&Bs[0][0] + 8192 + w * 1024;

  f32x4 acc[4][4] = {};

  const int rfA = lane & 15;
  const int rfK = (lane >> 4) * 8;

  for (int kt = 0; kt < K; kt += 2 * BK) {
    __syncthreads();
    // slice kt -> buffer 0
    gll16(gA + kt, ldsA);
    gll16(gB0 + kt, ldsB0);
    gll16(gB1 + kt, ldsB1);
    // slice kt+BK -> buffer 1
    gll16(gA + kt + BK, ldsA + 8192);
    gll16(gB0 + kt + BK, ldsB0 + 16384);
    gll16(gB1 + kt + BK, ldsB1 + 16384);
    __syncthreads();

#pragma unroll
    for (int h = 0; h < 2; h++) {
      const __hip_bfloat16* Ah = &As[h][0];
      const __hip_bfloat16* Bh = &Bs[h][0];
      short8 af[4], bfv[4];
#pragma unroll
      for (int i = 0; i < 4; i++)
        af[i] = *(const short8*)(Ah + (wm * 64 + i * 16 + rfA) * BK + rfK);
#pragma unroll
      for (int j = 0; j < 4; j++)
        bfv[j] = *(const short8*)(Bh + (wn * 64 + j * 16 + rfA) * BK + rfK);
#pragma unroll
      for (int i = 0; i < 4; i++)
#pragma unroll
        for (int j = 0; j < 4; j++)
          acc[i][j] = __builtin_amdgcn_mfma_f32_16x16x32_bf16(
              af[i], bfv[j], acc[i][j], 0, 0, 0);
    }
  }

  const int cq = lane >> 4;
#pragma unroll
  for (int i = 0; i < 4; i++) {
    int row = m0 + wm * 64 + i * 16 + cq * 4;
#pragma unroll
    for (int j = 0; j < 4; j++) {
      int col = n0 + wn * 64 + j * 16 + (lane & 15);
      float bz = bias[col];
#pragma unroll
      for (int r = 0; r < 4; r++) {
        float v = acc[i][j][r] + bz;
        Cout[(size_t)(row + r) * ldc + col] = __float2bfloat16(v);
      }
    }
  }
}

// --------------- compose GEMM: Wkk=Wkm@Wk, Wqq=Wqm@Wq (MFMA) ---------------
__global__ __launch_bounds__(256) void gemm_compose(
    const __hip_bfloat16* __restrict__ Wm_bf,
    const __hip_bfloat16* __restrict__ WT_bf,
    __hip_bfloat16* __restrict__ Wall) {
  constexpr int K = 512, BK = 32;
  const __hip_bfloat16* A  = Wm_bf + (size_t)blockIdx.z * 262144;
  const __hip_bfloat16* Bt = WT_bf + (size_t)blockIdx.z * 262144;
  __hip_bfloat16* C = Wall + (size_t)(512 + blockIdx.z * 512) * 512;
  __shared__ __align__(16) __hip_bfloat16 As[128 * BK];
  __shared__ __align__(16) __hip_bfloat16 Bs[128 * BK];

  const int tid  = threadIdx.x;
  const int lane = tid & 63;
  const int w    = tid >> 6;
  const int wm   = w >> 1;
  const int wn   = w & 1;
  const int m0   = blockIdx.y * 128;
  const int n0   = blockIdx.x * 128;

  const int rS0    = (w * 2 + 0) * 16 + (lane >> 2);
  const int rS1    = (w * 2 + 1) * 16 + (lane >> 2);
  const int kInRow = (lane & 3) * 8;
  const __hip_bfloat16* gA0 = A + (size_t)(m0 + rS0) * K + kInRow;
  const __hip_bfloat16* gA1 = A + (size_t)(m0 + rS1) * K + kInRow;
  const __hip_bfloat16* gB0 = Bt + (size_t)(n0 + rS0) * K + kInRow;
  const __hip_bfloat16* gB1 = Bt + (size_t)(n0 + rS1) * K + kInRow;
  char* ldsA0 = (char*)As + (w * 2 + 0) * 1024;
  char* ldsA1 = (char*)As + (w * 2 + 1) * 1024;
  char* ldsB0 = (char*)Bs + (w * 2 + 0) * 1024;
  char* ldsB1 = (char*)Bs + (w * 2 + 1) * 1024;

  f32x4 acc[4][4] = {};
  const int rfA = lane & 15;
  const int rfK = (lane >> 4) * 8;

  for (int kt = 0; kt < K; kt += BK) {
    __syncthreads();
    gll16(gA0 + kt, ldsA0);
    gll16(gA1 + kt, ldsA1);
    gll16(gB0 + kt, ldsB0);
    gll16(gB1 + kt, ldsB1);
    __syncthreads();

    short8 af[4], bf[4];
#pragma unroll
    for (int i = 0; i < 4; i++)
      af[i] = *(const short8*)(As + (wm * 64 + i * 16 + rfA) * BK + rfK);
#pragma unroll
    for (int j = 0; j < 4; j++)
      bf[j] = *(const short8*)(Bs + (wn * 64 + j * 16 + rfA) * BK + rfK);
#pragma unroll
    for (int i = 0; i < 4; i++)
#pragma unroll
      for (int j = 0; j < 4; j++)
        acc[i][j] = __builtin_amdgcn_mfma_f32_16x16x32_bf16(
            af[i], bf[j], acc[i][j], 0, 0, 0);
  }

  const int cq = lane >> 4;
#pragma unroll
  for (int i = 0; i < 4; i++) {
    int row = m0 + wm * 64 + i * 16 + cq * 4;
#pragma unroll
    for (int j = 0; j < 4; j++) {
      int col = n0 + wn * 64 + j * 16 + (lane & 15);
#pragma unroll
      for (int r = 0; r < 4; r++)
        C[(size_t)(row + r) * 512 + col] = __float2bfloat16(acc[i][j][r]);
    }
  }
}

// ------ fused: phasor + split-scan cumsum + LN + GEMM(Wo) + resid ----------
// grid 256 (= B*nC), 1024 threads (16 waves). One chunk (64 tokens) / block.
// (round-6 proven version: 45.8 us, VGPR 44)
__global__ __launch_bounds__(1024) void fused_pg(
    const __hip_bfloat16* __restrict__ VKQ,   // [16384,1536] planar
    const float* __restrict__ bp,             // [4096,512]
    const float* __restrict__ mod_scale,
    const float* __restrict__ ln_g, const float* __restrict__ ln_b,
    const __hip_bfloat16* __restrict__ WoB,   // [512,512] bf16
    const float* __restrict__ bo,
    const float* __restrict__ x,              // resid f32
    float* __restrict__ out) {
  __shared__ __hip_bfloat16 R[64 * RPAD];     // 66.5 KB
  __shared__ float Tr[512], Ti[512];          // seg0 complex totals
  const int tid    = threadIdx.x;
  const int seg    = tid >> 9;                // 0 or 1
  const int d      = tid & 511;
  const int blk    = blockIdx.x;
  const int token0 = blk * 64;
  const int sg0    = (blk & (NCHUNK - 1)) * 64;
  const float msc  = mod_scale[0];
  const float isd  = 0.044194173824159216f;   // 1/sqrt(512)

  // ---- phase 1a: per-segment local phasor + cumsum (32 tokens) ----
  {
    const int s0 = seg * 32;
    float mr = 0.f, mi = 0.f;
    const __hip_bfloat16* vb = VKQ + (size_t)(token0 + s0) * 1536 + d;
    const float* bb = bp + (size_t)(sg0 + s0) * 512 + d;
#pragma unroll 4
    for (int s = 0; s < 32; ++s) {
      float v  = __bfloat162float(vb[(size_t)s * 1536]);
      float km = __bfloat162float(vb[(size_t)s * 1536 + 512]);
      float qm = __bfloat162float(vb[(size_t)s * 1536 + 1024]);
      float b  = bb[(size_t)s * 512];
      float kp = b + km * msc;
      float qp = b + qm * msc;
      float sk, ck, sq, cq;
      __sincosf(kp, &sk, &ck);
      __sincosf(qp, &sq, &cq);
      mr += v * ck;
      mi += v * sk;
      R[(s0 + s) * RPAD + d] = __float2bfloat16((mr * cq + mi * sq) * isd);
    }
    if (seg == 0) {
      Tr[d] = mr;
      Ti[d] = mi;
    }
  }
  __syncthreads();

  // ---- phase 1b: fixup rows 32..63 with seg0 prefix (all 1024 threads) ----
  {
    const int r0 = 32 + seg * 16;             // 16 rows per thread-half
    const float pr = Tr[d] * isd;
    const float pi = Ti[d] * isd;
    const __hip_bfloat16* qb = VKQ + (size_t)(token0 + r0) * 1536 + 1024 + d;
    const float* bb = bp + (size_t)(sg0 + r0) * 512 + d;
#pragma unroll 4
    for (int s = 0; s < 16; ++s) {
      float qm = __bfloat162float(qb[(size_t)s * 1536]);
      float b  = bb[(size_t)s * 512];
      float qp = b + qm * msc;
      float sq, cq;
      __sincosf(qp, &sq, &cq);
      int idx = (r0 + s) * RPAD + d;
      float v = __bfloat162float(R[idx]) + pr * cq + pi * sq;
      R[idx] = __float2bfloat16(v);
    }
  }
  __syncthreads();

  // ---- LayerNorm in place (wave wv owns rows wv*4..+3) ----
  {
    const int lane = tid & 63;
    const int wv   = tid >> 6;                // 0..15
    float gj[8], bj[8];
#pragma unroll
    for (int j = 0; j < 8; j++) {
      int col = lane + 64 * j;
      gj[j] = ln_g[col];
      bj[j] = ln_b[col];
    }
    for (int rr = 0; rr < 4; ++rr) {
      int row = wv * 4 + rr;
      float vals[8], sum = 0.f, sq2 = 0.f;
#pragma unroll
      for (int j = 0; j < 8; j++) {
        float v = __bfloat162float(R[row * RPAD + lane + 64 * j]);
        vals[j] = v;
        sum += v;
        sq2 += v * v;
      }
#pragma unroll
      for (int off = 32; off; off >>= 1) {
        sum += __shfl_xor(sum, off, 64);
        sq2 += __shfl_xor(sq2, off, 64);
      }
      float mu   = sum * (1.f / 512.f);
      float var  = sq2 * (1.f / 512.f) - mu * mu;
      float rstd = rsqrtf(var + 1e-5f);
#pragma unroll
      for (int j = 0; j < 8; j++) {
        float nv = (vals[j] - mu) * rstd * gj[j] + bj[j];
        R[row * RPAD + lane + 64 * j] = __float2bfloat16(nv);
      }
    }
  }
  __syncthreads();

  // ---- phase 2: C(64x512) = R @ WoB^T + bo + x -> out (16 waves) ----
  {
    const int lane = tid & 63;
    const int w    = tid >> 6;                // wave 0..15 -> cols w*32..+31
    const int rfA  = lane & 15;
    const int rfK  = (lane >> 4) * 8;
    f32x4 acc[4][2] = {};

    for (int kt = 0; kt < 512; kt += 32) {
      short8 af[4], bf[2];
#pragma unroll
      for (int j = 0; j < 2; j++) {
        int col = w * 32 + j * 16 + rfA;
        bf[j] = *(const short8*)(WoB + (size_t)col * 512 + kt + rfK);
      }
#pragma unroll
      for (int i = 0; i < 4; i++)
        af[i] = *(const short8*)(R + (i * 16 + rfA) * RPAD + kt + rfK);
#pragma unroll
      for (int i = 0; i < 4; i++)
#pragma unroll
        for (int j = 0; j < 2; j++)
          acc[i][j] = __builtin_amdgcn_mfma_f32_16x16x32_bf16(
              af[i], bf[j], acc[i][j], 0, 0, 0);
    }

    const int cq = lane >> 4;
    float bz[2];
#pragma unroll
    for (int j = 0; j < 2; j++) bz[j] = bo[w * 32 + j * 16 + (lane & 15)];
#pragma unroll
    for (int i = 0; i < 4; i++) {
      int row = token0 + i * 16 + cq * 4;
#pragma unroll
      for (int j = 0; j < 2; j++) {
        int col = w * 32 + j * 16 + (lane & 15);
#pragma unroll
        for (int r = 0; r < 4; r++) {
          size_t o = (size_t)(row + r) * 512 + col;
          out[o] = acc[i][j][r] + bz[j] + x[o];
        }
      }
    }
  }
}

// ------------------------------- launcher ----------------------------------
extern "C" void kernel_launch(void* const* d_in, const int* in_sizes, int n_in,
                              void* d_out, int out_size, void* d_ws,
                              size_t ws_size, hipStream_t stream) {
  const float* x    = (const float*)d_in[0];
  const float* bp   = (const float*)d_in[1];
  const float* Wk   = (const float*)d_in[2];
  const float* bk   = (const float*)d_in[3];
  const float* Wv   = (const float*)d_in[4];
  const float* bv   = (const float*)d_in[5];
  const float* Wq   = (const float*)d_in[6];
  const float* bq   = (const float*)d_in[7];
  const float* Wkm  = (const float*)d_in[8];
  const float* bkm  = (const float*)d_in[9];
  const float* Wqm  = (const float*)d_in[10];
  const float* bqm  = (const float*)d_in[11];
  const float* msc  = (const float*)d_in[12];
  const float* lng  = (const float*)d_in[13];
  const float* lnb  = (const float*)d_in[14];
  const float* Wo   = (const float*)d_in[15];
  const float* bo   = (const float*)d_in[16];
  float* out = (float*)d_out;

  char* ws = (char*)d_ws;
  __hip_bfloat16* x_bf  = (__hip_bfloat16*)ws;  ws += (size_t)M_TOK * DIM * 2;
  __hip_bfloat16* Wall  = (__hip_bfloat16*)ws;  ws += (size_t)2048 * 512 * 2;
  __hip_bfloat16* Wm_bf = (__hip_bfloat16*)ws;  ws += (size_t)2 * 262144 * 2;
  __hip_bfloat16* WT_bf = (__hip_bfloat16*)ws;  ws += (size_t)2 * 262144 * 2;
  float*          bc1   = (float*)ws;           ws += 1536 * 4;
  __hip_bfloat16* VKQ   = (__hip_bfloat16*)ws;  ws += (size_t)M_TOK * 1536 * 2;

  // 1) merged prep: cvt x + pack/cvt/transpose weights + compose biases
  prep_all<<<9600, 256, 0, stream>>>(x, x_bf, Wv, Wo, bv, Wkm, Wqm, Wk, Wq,
                                     bk, bkm, bq, bqm, Wall, bc1, Wm_bf,
                                     WT_bf);
  // 2) MFMA compose: Wkk, Wqq -> Wall rows 512..1535
  gemm_compose<<<dim3(4, 4, 2), 256, 0, stream>>>(Wm_bf, WT_bf, Wall);
  // 3) VKQ = x @ [Wv|Wkk|Wqq]^T + bias, planar [16384,1536]
  gemm_bt<<<dim3(768), 512, 0, stream>>>(x_bf, DIM, Wall, bc1, VKQ, 1536);
  // 4) fused phasor + split-scan cumsum + LN + GEMM(Wo) + bo + resid -> out
  fused_pg<<<256, 1024, 0, stream>>>(VKQ, bp, msc, lng, lnb,
                                     Wall + (size_t)1536 * 512, bo, x, out);
}